// Round 1
// baseline (1570.387 us; speedup 1.0000x reference)
//
#include <hip/hip_runtime.h>
#include <math.h>

#define NNODES 100000
#define INF 128
#define HIDC 64
#define NHEADS 2
#define OUTC 16
#define GRAPHS 100
#define SLOPE 0.2f

__device__ __forceinline__ float lrelu(float v) { return v > 0.f ? v : SLOPE * v; }

__device__ __forceinline__ void atomAddG(float* p, float v) { unsafeAtomicAdd(p, v); }

// ---------------- GEMM: C[M,Nc] = op(A)[M,K] @ B[K,Nc], row-major fp32 ----------------
template <bool RELU_BIAS_A>
__global__ __launch_bounds__(256) void gemm_kernel(const float* __restrict__ A,
                                                   const float* __restrict__ B,
                                                   float* __restrict__ C,
                                                   const float* __restrict__ biasA,
                                                   int M, int K, int Nc) {
    constexpr int BM = 64, BN = 64, BK = 32;
    __shared__ float As[BM][BK + 1];
    __shared__ float Bs[BK][BN];
    const int tid = threadIdx.x;
    const int row0 = blockIdx.x * BM;
    const int col0 = blockIdx.y * BN;
    float acc[4][4] = {};
    const int tx = tid & 15, ty = tid >> 4;
    const int ka = tid & 31, ra = tid >> 5;  // A tile: 32 k × 8-row groups
    const int cb = tid & 63, kb = tid >> 6;  // B tile: 64 col × 4-k groups

    for (int k0 = 0; k0 < K; k0 += BK) {
#pragma unroll
        for (int p = 0; p < 8; ++p) {
            int r = ra + p * 8;
            int gr = row0 + r;
            float v = 0.f;
            if (gr < M) {
                v = A[(size_t)gr * K + (k0 + ka)];
                if (RELU_BIAS_A) {
                    v += biasA[k0 + ka];
                    v = v > 0.f ? v : 0.f;
                }
            }
            As[r][ka] = v;
        }
#pragma unroll
        for (int p = 0; p < 8; ++p) {
            int kk = kb + p * 4;
            Bs[kk][cb] = B[(size_t)(k0 + kk) * Nc + (col0 + cb)];
        }
        __syncthreads();
#pragma unroll
        for (int kk = 0; kk < BK; ++kk) {
            float a[4];
#pragma unroll
            for (int i = 0; i < 4; ++i) a[i] = As[ty * 4 + i][kk];
            float4 b4 = *(const float4*)&Bs[kk][tx * 4];
            float b[4] = {b4.x, b4.y, b4.z, b4.w};
#pragma unroll
            for (int i = 0; i < 4; ++i)
#pragma unroll
                for (int j = 0; j < 4; ++j) acc[i][j] = fmaf(a[i], b[j], acc[i][j]);
        }
        __syncthreads();
    }
#pragma unroll
    for (int i = 0; i < 4; ++i) {
        int gr = row0 + ty * 4 + i;
        if (gr < M) {
            float4 v = {acc[i][0], acc[i][1], acc[i][2], acc[i][3]};
            *(float4*)&C[(size_t)gr * Nc + col0 + tx * 4] = v;
        }
    }
}

// ---------------- attention coefficients ----------------
// layer1: h [n,2*64]; att_src/att_dst [2,64]; out asrc/adst [n,2] interleaved
__global__ void alpha1_kernel(const float* __restrict__ h, const float* __restrict__ att_src,
                              const float* __restrict__ att_dst, float* __restrict__ asrc,
                              float* __restrict__ adst, int n) {
    int lane = threadIdx.x & 63;
    int wid = (blockIdx.x * blockDim.x + threadIdx.x) >> 6;
    int nw = (gridDim.x * blockDim.x) >> 6;
    float as0c = att_src[lane], as1c = att_src[64 + lane];
    float ad0c = att_dst[lane], ad1c = att_dst[64 + lane];
    for (int i = wid; i < n; i += nw) {
        const float* row = h + (size_t)i * 128;
        float v0 = row[lane], v1 = row[64 + lane];
        float s0 = v0 * as0c, s1 = v1 * as1c;
        float d0 = v0 * ad0c, d1 = v1 * ad1c;
#pragma unroll
        for (int off = 32; off; off >>= 1) {
            s0 += __shfl_xor(s0, off);
            s1 += __shfl_xor(s1, off);
            d0 += __shfl_xor(d0, off);
            d1 += __shfl_xor(d1, off);
        }
        if (lane == 0) {
            asrc[2 * i] = s0;
            asrc[2 * i + 1] = s1;
            adst[2 * i] = d0;
            adst[2 * i + 1] = d1;
        }
    }
}

// layer2: h [n,64]; att [1,64]; out asrc/adst [n]
__global__ void alpha2_kernel(const float* __restrict__ h, const float* __restrict__ att_src,
                              const float* __restrict__ att_dst, float* __restrict__ asrc,
                              float* __restrict__ adst, int n) {
    int lane = threadIdx.x & 63;
    int wid = (blockIdx.x * blockDim.x + threadIdx.x) >> 6;
    int nw = (gridDim.x * blockDim.x) >> 6;
    float asc = att_src[lane], adc = att_dst[lane];
    for (int i = wid; i < n; i += nw) {
        float v = h[(size_t)i * 64 + lane];
        float s = v * asc, d = v * adc;
#pragma unroll
        for (int off = 32; off; off >>= 1) {
            s += __shfl_xor(s, off);
            d += __shfl_xor(d, off);
        }
        if (lane == 0) {
            asrc[i] = s;
            adst[i] = d;
        }
    }
}

// ---------------- softmax denominators (no max-shift; logits bounded) ----------------
__global__ void den_init1(const float* __restrict__ asrc, const float* __restrict__ adst,
                          float* __restrict__ den, int n2) {
    int t = blockIdx.x * blockDim.x + threadIdx.x;
    if (t < n2) den[t] = __expf(lrelu(asrc[t] + adst[t]));  // self-loop term, also zero-init
}

__global__ void den_edge1(const int* __restrict__ ei, int E, const float* __restrict__ asrc,
                          const float* __restrict__ adst, float* __restrict__ den) {
    int stride = gridDim.x * blockDim.x;
    for (int e = blockIdx.x * blockDim.x + threadIdx.x; e < E; e += stride) {
        int s = ei[e], d = ei[E + e];
        float2 as = *(const float2*)(asrc + 2 * s);
        float2 ad = *(const float2*)(adst + 2 * d);
        atomAddG(&den[2 * d], __expf(lrelu(as.x + ad.x)));
        atomAddG(&den[2 * d + 1], __expf(lrelu(as.y + ad.y)));
    }
}

__global__ void den_init2(const float* __restrict__ asrc, const float* __restrict__ adst,
                          float* __restrict__ den, int n) {
    int t = blockIdx.x * blockDim.x + threadIdx.x;
    if (t < n) den[t] = __expf(lrelu(asrc[t] + adst[t]));
}

__global__ void den_edge2(const int* __restrict__ ei, int E, const float* __restrict__ asrc,
                          const float* __restrict__ adst, float* __restrict__ den) {
    int stride = gridDim.x * blockDim.x;
    for (int e = blockIdx.x * blockDim.x + threadIdx.x; e < E; e += stride) {
        int s = ei[e], d = ei[E + e];
        atomAddG(&den[d], __expf(lrelu(asrc[s] + adst[d])));
    }
}

// ---------------- aggregation ----------------
// layer1: self term (writes = zero-init), then edge atomics. h row = 128 (2 heads × 64)
__global__ void agg_init1(const float* __restrict__ h, const float* __restrict__ asrc,
                          const float* __restrict__ adst, const float* __restrict__ den,
                          float* __restrict__ outb, int n) {
    int lane = threadIdx.x & 63;
    int wid = (blockIdx.x * blockDim.x + threadIdx.x) >> 6;
    int nw = (gridDim.x * blockDim.x) >> 6;
    for (int i = wid; i < n; i += nw) {
        float2 as = *(const float2*)(asrc + 2 * i);
        float2 ad = *(const float2*)(adst + 2 * i);
        float2 dn = *(const float2*)(den + 2 * i);
        float a0 = __expf(lrelu(as.x + ad.x)) / dn.x;
        float a1 = __expf(lrelu(as.y + ad.y)) / dn.y;
        const float* hs = h + (size_t)i * 128;
        float* od = outb + (size_t)i * 128;
        od[lane] = hs[lane] * a0;
        od[64 + lane] = hs[64 + lane] * a1;
    }
}

__global__ void agg_edge1(const int* __restrict__ ei, int E, const float* __restrict__ h,
                          const float* __restrict__ asrc, const float* __restrict__ adst,
                          const float* __restrict__ den, float* __restrict__ outb) {
    int lane = threadIdx.x & 63;
    int wid = (blockIdx.x * blockDim.x + threadIdx.x) >> 6;
    int nw = (gridDim.x * blockDim.x) >> 6;
    for (int e = wid; e < E; e += nw) {
        int s = ei[e], d = ei[E + e];
        float2 as = *(const float2*)(asrc + 2 * s);
        float2 ad = *(const float2*)(adst + 2 * d);
        float2 dn = *(const float2*)(den + 2 * d);
        float a0 = __expf(lrelu(as.x + ad.x)) / dn.x;
        float a1 = __expf(lrelu(as.y + ad.y)) / dn.y;
        const float* hs = h + (size_t)s * 128;
        float* od = outb + (size_t)d * 128;
        atomAddG(&od[lane], hs[lane] * a0);
        atomAddG(&od[64 + lane], hs[64 + lane] * a1);
    }
}

// layer2: h row = 64, single head
__global__ void agg_init2(const float* __restrict__ h, const float* __restrict__ asrc,
                          const float* __restrict__ adst, const float* __restrict__ den,
                          float* __restrict__ outb, int n) {
    int lane = threadIdx.x & 63;
    int wid = (blockIdx.x * blockDim.x + threadIdx.x) >> 6;
    int nw = (gridDim.x * blockDim.x) >> 6;
    for (int i = wid; i < n; i += nw) {
        float a = __expf(lrelu(asrc[i] + adst[i])) / den[i];
        outb[(size_t)i * 64 + lane] = h[(size_t)i * 64 + lane] * a;
    }
}

__global__ void agg_edge2(const int* __restrict__ ei, int E, const float* __restrict__ h,
                          const float* __restrict__ asrc, const float* __restrict__ adst,
                          const float* __restrict__ den, float* __restrict__ outb) {
    int lane = threadIdx.x & 63;
    int wid = (blockIdx.x * blockDim.x + threadIdx.x) >> 6;
    int nw = (gridDim.x * blockDim.x) >> 6;
    for (int e = wid; e < E; e += nw) {
        int s = ei[e], d = ei[E + e];
        float a = __expf(lrelu(asrc[s] + adst[d])) / den[d];
        atomAddG(&outb[(size_t)d * 64 + lane], h[(size_t)s * 64 + lane] * a);
    }
}

// ---------------- mean pool (batch sorted) ----------------
#define NPB 256
__global__ __launch_bounds__(256) void pool_kernel(const float* __restrict__ h,
                                                   const int* __restrict__ batch,
                                                   float* __restrict__ sums,
                                                   float* __restrict__ cnt, int n) {
    __shared__ float ls[GRAPHS * HIDC];
    __shared__ float lc[GRAPHS];
    int base = blockIdx.x * NPB;
    for (int t = threadIdx.x; t < GRAPHS * HIDC; t += blockDim.x) ls[t] = 0.f;
    for (int t = threadIdx.x; t < GRAPHS; t += blockDim.x) lc[t] = 0.f;
    __syncthreads();
    int wave = threadIdx.x >> 6, lane = threadIdx.x & 63;
    int end = base + NPB < n ? base + NPB : n;
    for (int i = base + wave; i < end; i += 4) {
        int g = batch[i];
        unsafeAtomicAdd(&ls[g * HIDC + lane], h[(size_t)i * HIDC + lane]);
        if (lane == 0) unsafeAtomicAdd(&lc[g], 1.f);
    }
    __syncthreads();
    int gmin = batch[base];
    int gmax = batch[end - 1];
    int ng = gmax - gmin + 1;
    for (int t = threadIdx.x; t < ng * HIDC; t += blockDim.x) {
        int g = gmin + t / HIDC, c = t % HIDC;
        atomAddG(&sums[g * HIDC + c], ls[g * HIDC + c]);
    }
    for (int g = gmin + (int)threadIdx.x; g <= gmax; g += blockDim.x)
        atomAddG(&cnt[g], lc[g]);
}

// ---------------- final linear: out[g,o] = (sums[g]/max(cnt,1) + b2) @ Wl + bl ----------------
__global__ void final_kernel(const float* __restrict__ sums, const float* __restrict__ cnt,
                             const float* __restrict__ b2, const float* __restrict__ Wl,
                             const float* __restrict__ bl, float* __restrict__ out) {
    int t = blockIdx.x * blockDim.x + threadIdx.x;
    if (t < GRAPHS * OUTC) {
        int g = t / OUTC, o = t % OUTC;
        float c = cnt[g];
        c = c > 1.f ? c : 1.f;
        float inv = 1.f / c;
        float acc = bl[o];
        for (int k = 0; k < HIDC; ++k)
            acc += (sums[g * HIDC + k] * inv + b2[k]) * Wl[k * OUTC + o];
        out[t] = acc;
    }
}

extern "C" void kernel_launch(void* const* d_in, const int* in_sizes, int n_in, void* d_out,
                              int out_size, void* d_ws, size_t ws_size, hipStream_t stream) {
    const float* x = (const float*)d_in[0];
    const int* ei = (const int*)d_in[1];
    const int* batch = (const int*)d_in[2];
    const float* W1 = (const float*)d_in[3];
    const float* att_src1 = (const float*)d_in[4];
    const float* att_dst1 = (const float*)d_in[5];
    const float* b1 = (const float*)d_in[6];
    const float* W2 = (const float*)d_in[7];
    const float* att_src2 = (const float*)d_in[8];
    const float* att_dst2 = (const float*)d_in[9];
    const float* b2 = (const float*)d_in[10];
    const float* Wl = (const float*)d_in[11];
    const float* bl = (const float*)d_in[12];
    float* out = (float*)d_out;

    const int n = in_sizes[2];
    const int E = in_sizes[1] / 2;

    float* ws = (float*)d_ws;
    float* bufA = ws;                          // n*128: h1, later h2 (n*64)
    float* bufB = ws + (size_t)n * 128;        // n*128: conv1 out / hrelu, later conv2 out
    float* S = bufB + (size_t)n * 128;
    float* asrc1 = S;                          // n*2
    float* adst1 = S + 2 * (size_t)n;          // n*2
    float* den1 = S + 4 * (size_t)n;           // n*2
    float* asrc2 = S + 6 * (size_t)n;          // n
    float* adst2 = S + 7 * (size_t)n;          // n
    float* den2 = S + 8 * (size_t)n;           // n
    float* sums = S + 9 * (size_t)n;           // G*64
    float* cnt = sums + GRAPHS * HIDC;         // G

    // ---- layer 1 ----
    dim3 g1((n + 63) / 64, 2);
    gemm_kernel<false><<<g1, 256, 0, stream>>>(x, W1, bufA, nullptr, n, 128, 128);
    alpha1_kernel<<<2048, 256, 0, stream>>>(bufA, att_src1, att_dst1, asrc1, adst1, n);
    den_init1<<<(2 * n + 255) / 256, 256, 0, stream>>>(asrc1, adst1, den1, 2 * n);
    den_edge1<<<2048, 256, 0, stream>>>(ei, E, asrc1, adst1, den1);
    agg_init1<<<2048, 256, 0, stream>>>(bufA, asrc1, adst1, den1, bufB, n);
    agg_edge1<<<4096, 256, 0, stream>>>(ei, E, bufA, asrc1, adst1, den1, bufB);

    // ---- layer 2 (bias1+ReLU fused into A-load of gemm2) ----
    dim3 g2((n + 63) / 64, 1);
    gemm_kernel<true><<<g2, 256, 0, stream>>>(bufB, W2, bufA, b1, n, 128, 64);
    alpha2_kernel<<<2048, 256, 0, stream>>>(bufA, att_src2, att_dst2, asrc2, adst2, n);
    den_init2<<<(n + 255) / 256, 256, 0, stream>>>(asrc2, adst2, den2, n);
    den_edge2<<<2048, 256, 0, stream>>>(ei, E, asrc2, adst2, den2);
    agg_init2<<<2048, 256, 0, stream>>>(bufA, asrc2, adst2, den2, bufB, n);
    agg_edge2<<<4096, 256, 0, stream>>>(ei, E, bufA, asrc2, adst2, den2, bufB);

    // ---- pool + final linear (bias2 folded into final) ----
    hipMemsetAsync(sums, 0, (GRAPHS * HIDC + GRAPHS) * sizeof(float), stream);
    pool_kernel<<<(n + NPB - 1) / NPB, 256, 0, stream>>>(bufB, batch, sums, cnt, n);
    final_kernel<<<(GRAPHS * OUTC + 255) / 256, 256, 0, stream>>>(sums, cnt, b2, Wl, bl, out);
}

// Round 2
// 763.707 us; speedup vs baseline: 2.0563x; 2.0563x over previous
//
#include <hip/hip_runtime.h>
#include <math.h>

#define NNODES 100000
#define HIDC 64
#define OUTC 16
#define GRAPHS 100
#define SLOPE 0.2f

__device__ __forceinline__ float lrelu(float v) { return v > 0.f ? v : SLOPE * v; }
__device__ __forceinline__ void atomAddG(float* p, float v) { unsafeAtomicAdd(p, v); }

// ---------------- GEMM: C[M,Nc] = op(A)[M,K] @ B[K,Nc], row-major fp32 ----------------
template <bool RELU_BIAS_A>
__global__ __launch_bounds__(256) void gemm_kernel(const float* __restrict__ A,
                                                   const float* __restrict__ B,
                                                   float* __restrict__ C,
                                                   const float* __restrict__ biasA,
                                                   int M, int K, int Nc) {
    constexpr int BM = 64, BN = 64, BK = 32;
    __shared__ float As[BM][BK + 1];
    __shared__ float Bs[BK][BN];
    const int tid = threadIdx.x;
    const int row0 = blockIdx.x * BM;
    const int col0 = blockIdx.y * BN;
    float acc[4][4] = {};
    const int tx = tid & 15, ty = tid >> 4;
    const int ka = tid & 31, ra = tid >> 5;
    const int cb = tid & 63, kb = tid >> 6;

    for (int k0 = 0; k0 < K; k0 += BK) {
#pragma unroll
        for (int p = 0; p < 8; ++p) {
            int r = ra + p * 8;
            int gr = row0 + r;
            float v = 0.f;
            if (gr < M) {
                v = A[(size_t)gr * K + (k0 + ka)];
                if (RELU_BIAS_A) {
                    v += biasA[k0 + ka];
                    v = v > 0.f ? v : 0.f;
                }
            }
            As[r][ka] = v;
        }
#pragma unroll
        for (int p = 0; p < 8; ++p) {
            int kk = kb + p * 4;
            Bs[kk][cb] = B[(size_t)(k0 + kk) * Nc + (col0 + cb)];
        }
        __syncthreads();
#pragma unroll
        for (int kk = 0; kk < BK; ++kk) {
            float a[4];
#pragma unroll
            for (int i = 0; i < 4; ++i) a[i] = As[ty * 4 + i][kk];
            float4 b4 = *(const float4*)&Bs[kk][tx * 4];
            float b[4] = {b4.x, b4.y, b4.z, b4.w};
#pragma unroll
            for (int i = 0; i < 4; ++i)
#pragma unroll
                for (int j = 0; j < 4; ++j) acc[i][j] = fmaf(a[i], b[j], acc[i][j]);
        }
        __syncthreads();
    }
#pragma unroll
    for (int i = 0; i < 4; ++i) {
        int gr = row0 + ty * 4 + i;
        if (gr < M) {
            float4 v = {acc[i][0], acc[i][1], acc[i][2], acc[i][3]};
            *(float4*)&C[(size_t)gr * Nc + col0 + tx * 4] = v;
        }
    }
}

// ---------------- attention coefficients ----------------
__global__ void alpha1_kernel(const float* __restrict__ h, const float* __restrict__ att_src,
                              const float* __restrict__ att_dst, float* __restrict__ asrc,
                              float* __restrict__ adst, int n) {
    int lane = threadIdx.x & 63;
    int wid = (blockIdx.x * blockDim.x + threadIdx.x) >> 6;
    int nw = (gridDim.x * blockDim.x) >> 6;
    float as0c = att_src[lane], as1c = att_src[64 + lane];
    float ad0c = att_dst[lane], ad1c = att_dst[64 + lane];
    for (int i = wid; i < n; i += nw) {
        const float* row = h + (size_t)i * 128;
        float v0 = row[lane], v1 = row[64 + lane];
        float s0 = v0 * as0c, s1 = v1 * as1c;
        float d0 = v0 * ad0c, d1 = v1 * ad1c;
#pragma unroll
        for (int off = 32; off; off >>= 1) {
            s0 += __shfl_xor(s0, off);
            s1 += __shfl_xor(s1, off);
            d0 += __shfl_xor(d0, off);
            d1 += __shfl_xor(d1, off);
        }
        if (lane == 0) {
            asrc[2 * i] = s0;
            asrc[2 * i + 1] = s1;
            adst[2 * i] = d0;
            adst[2 * i + 1] = d1;
        }
    }
}

__global__ void alpha2_kernel(const float* __restrict__ h, const float* __restrict__ att_src,
                              const float* __restrict__ att_dst, float* __restrict__ asrc,
                              float* __restrict__ adst, int n) {
    int lane = threadIdx.x & 63;
    int wid = (blockIdx.x * blockDim.x + threadIdx.x) >> 6;
    int nw = (gridDim.x * blockDim.x) >> 6;
    float asc = att_src[lane], adc = att_dst[lane];
    for (int i = wid; i < n; i += nw) {
        float v = h[(size_t)i * 64 + lane];
        float s = v * asc, d = v * adc;
#pragma unroll
        for (int off = 32; off; off >>= 1) {
            s += __shfl_xor(s, off);
            d += __shfl_xor(d, off);
        }
        if (lane == 0) {
            asrc[i] = s;
            adst[i] = d;
        }
    }
}

// ---------------- CSR build (dst -> list of src) ----------------
__global__ void deg_kernel(const int* __restrict__ ei, int E, int* __restrict__ deg) {
    int stride = gridDim.x * blockDim.x;
    for (int e = blockIdx.x * blockDim.x + threadIdx.x; e < E; e += stride)
        atomicAdd(&deg[ei[E + e]], 1);
}

// per-block exclusive scan over 1024 elems (256 thr x 4)
__global__ __launch_bounds__(256) void scan_block(const int* __restrict__ deg,
                                                  int* __restrict__ rp,
                                                  int* __restrict__ bsums, int n) {
    __shared__ int sh[256];
    int base = blockIdx.x * 1024;
    int t = threadIdx.x;
    int i0 = base + t * 4;
    int v0 = 0, v1 = 0, v2 = 0, v3 = 0;
    if (i0 + 3 < n) {
        int4 q = *(const int4*)(deg + i0);
        v0 = q.x; v1 = q.y; v2 = q.z; v3 = q.w;
    } else {
        if (i0 < n) v0 = deg[i0];
        if (i0 + 1 < n) v1 = deg[i0 + 1];
        if (i0 + 2 < n) v2 = deg[i0 + 2];
        if (i0 + 3 < n) v3 = deg[i0 + 3];
    }
    int tsum = v0 + v1 + v2 + v3;
    sh[t] = tsum;
    __syncthreads();
#pragma unroll
    for (int off = 1; off < 256; off <<= 1) {
        int val = (t >= off) ? sh[t - off] : 0;
        __syncthreads();
        sh[t] += val;
        __syncthreads();
    }
    if (t == 255) bsums[blockIdx.x] = sh[255];
    int p = sh[t] - tsum;  // exclusive prefix for this thread
    if (i0 < n) rp[i0] = p;
    p += v0;
    if (i0 + 1 < n) rp[i0 + 1] = p;
    p += v1;
    if (i0 + 2 < n) rp[i0 + 2] = p;
    p += v2;
    if (i0 + 3 < n) rp[i0 + 3] = p;
}

__global__ void scan_bsums(int* __restrict__ bsums, int nb) {
    if (threadIdx.x == 0 && blockIdx.x == 0) {
        int acc = 0;
        for (int b = 0; b < nb; ++b) {
            int v = bsums[b];
            bsums[b] = acc;
            acc += v;
        }
    }
}

__global__ void scan_add(int* __restrict__ rp, const int* __restrict__ bsums,
                         int* __restrict__ cursor, int n, int E) {
    int idx = blockIdx.x * blockDim.x + threadIdx.x;
    if (idx < n) {
        int v = rp[idx] + bsums[idx >> 10];
        rp[idx] = v;
        cursor[idx] = v;
    }
    if (idx == n) rp[n] = E;
}

__global__ void scatter_edges(const int* __restrict__ ei, int E, int* __restrict__ cursor,
                              int* __restrict__ col) {
    int stride = gridDim.x * blockDim.x;
    for (int e = blockIdx.x * blockDim.x + threadIdx.x; e < E; e += stride) {
        int s = ei[e], d = ei[E + e];
        int pos = atomicAdd(&cursor[d], 1);
        col[pos] = s;
    }
}

// ---------------- fused per-node GAT aggregation (gather, no atomics) ----------------
// layer1: 2 heads x 64 ch; lane -> float2 at h[i*128 + 2*lane]; head = lane/32
__global__ __launch_bounds__(256) void gat_agg1(const int* __restrict__ rowptr,
                                                const int* __restrict__ col,
                                                const float* __restrict__ h,
                                                const float* __restrict__ asrc,
                                                const float* __restrict__ adst,
                                                float* __restrict__ outb, int n) {
    int lane = threadIdx.x & 63;
    int i = (blockIdx.x * blockDim.x + threadIdx.x) >> 6;
    if (i >= n) return;
    float2 ad = *(const float2*)(adst + 2 * i);
    float2 ass = *(const float2*)(asrc + 2 * i);
    float w0 = __expf(lrelu(ass.x + ad.x));
    float w1 = __expf(lrelu(ass.y + ad.y));
    const float2* h2 = (const float2*)h;
    float2 hv = h2[(size_t)i * 64 + lane];
    float w = (lane < 32) ? w0 : w1;
    float accx = hv.x * w, accy = hv.y * w;
    float den0 = w0, den1 = w1;
    int e = rowptr[i], end = rowptr[i + 1];
    int s_next = (e < end) ? col[e] : 0;
    while (e < end) {
        int s = s_next;
        ++e;
        if (e < end) s_next = col[e];
        float2 as = *(const float2*)(asrc + 2 * s);
        float2 hs = h2[(size_t)s * 64 + lane];
        float e0 = __expf(lrelu(as.x + ad.x));
        float e1 = __expf(lrelu(as.y + ad.y));
        float we = (lane < 32) ? e0 : e1;
        accx = fmaf(hs.x, we, accx);
        accy = fmaf(hs.y, we, accy);
        den0 += e0;
        den1 += e1;
    }
    float inv = 1.f / ((lane < 32) ? den0 : den1);
    float2 o = {accx * inv, accy * inv};
    ((float2*)outb)[(size_t)i * 64 + lane] = o;
}

// layer2: 1 head x 64 ch; lane -> h[i*64 + lane]
__global__ __launch_bounds__(256) void gat_agg2(const int* __restrict__ rowptr,
                                                const int* __restrict__ col,
                                                const float* __restrict__ h,
                                                const float* __restrict__ asrc,
                                                const float* __restrict__ adst,
                                                float* __restrict__ outb, int n) {
    int lane = threadIdx.x & 63;
    int i = (blockIdx.x * blockDim.x + threadIdx.x) >> 6;
    if (i >= n) return;
    float ad = adst[i];
    float wself = __expf(lrelu(asrc[i] + ad));
    float acc = h[(size_t)i * 64 + lane] * wself;
    float den = wself;
    int e = rowptr[i], end = rowptr[i + 1];
    int s_next = (e < end) ? col[e] : 0;
    while (e < end) {
        int s = s_next;
        ++e;
        if (e < end) s_next = col[e];
        float as = asrc[s];
        float hs = h[(size_t)s * 64 + lane];
        float we = __expf(lrelu(as + ad));
        acc = fmaf(hs, we, acc);
        den += we;
    }
    outb[(size_t)i * 64 + lane] = acc / den;
}

// ---------------- mean pool (batch sorted) ----------------
#define NPB 256
__global__ __launch_bounds__(256) void pool_kernel(const float* __restrict__ h,
                                                   const int* __restrict__ batch,
                                                   float* __restrict__ sums,
                                                   float* __restrict__ cnt, int n) {
    __shared__ float ls[GRAPHS * HIDC];
    __shared__ float lc[GRAPHS];
    int base = blockIdx.x * NPB;
    for (int t = threadIdx.x; t < GRAPHS * HIDC; t += blockDim.x) ls[t] = 0.f;
    for (int t = threadIdx.x; t < GRAPHS; t += blockDim.x) lc[t] = 0.f;
    __syncthreads();
    int wave = threadIdx.x >> 6, lane = threadIdx.x & 63;
    int end = base + NPB < n ? base + NPB : n;
    for (int i = base + wave; i < end; i += 4) {
        int g = batch[i];
        unsafeAtomicAdd(&ls[g * HIDC + lane], h[(size_t)i * HIDC + lane]);
        if (lane == 0) unsafeAtomicAdd(&lc[g], 1.f);
    }
    __syncthreads();
    int gmin = batch[base];
    int gmax = batch[end - 1];
    int ng = gmax - gmin + 1;
    for (int t = threadIdx.x; t < ng * HIDC; t += blockDim.x) {
        int g = gmin + t / HIDC, c = t % HIDC;
        atomAddG(&sums[g * HIDC + c], ls[g * HIDC + c]);
    }
    for (int g = gmin + (int)threadIdx.x; g <= gmax; g += blockDim.x)
        atomAddG(&cnt[g], lc[g]);
}

// ---------------- final linear ----------------
__global__ void final_kernel(const float* __restrict__ sums, const float* __restrict__ cnt,
                             const float* __restrict__ b2, const float* __restrict__ Wl,
                             const float* __restrict__ bl, float* __restrict__ out) {
    int t = blockIdx.x * blockDim.x + threadIdx.x;
    if (t < GRAPHS * OUTC) {
        int g = t / OUTC, o = t % OUTC;
        float c = cnt[g];
        c = c > 1.f ? c : 1.f;
        float inv = 1.f / c;
        float acc = bl[o];
        for (int k = 0; k < HIDC; ++k)
            acc += (sums[g * HIDC + k] * inv + b2[k]) * Wl[k * OUTC + o];
        out[t] = acc;
    }
}

extern "C" void kernel_launch(void* const* d_in, const int* in_sizes, int n_in, void* d_out,
                              int out_size, void* d_ws, size_t ws_size, hipStream_t stream) {
    const float* x = (const float*)d_in[0];
    const int* ei = (const int*)d_in[1];
    const int* batch = (const int*)d_in[2];
    const float* W1 = (const float*)d_in[3];
    const float* att_src1 = (const float*)d_in[4];
    const float* att_dst1 = (const float*)d_in[5];
    const float* b1 = (const float*)d_in[6];
    const float* W2 = (const float*)d_in[7];
    const float* att_src2 = (const float*)d_in[8];
    const float* att_dst2 = (const float*)d_in[9];
    const float* b2 = (const float*)d_in[10];
    const float* Wl = (const float*)d_in[11];
    const float* bl = (const float*)d_in[12];
    float* out = (float*)d_out;

    const int n = in_sizes[2];
    const int E = in_sizes[1] / 2;

    float* ws = (float*)d_ws;
    float* bufA = ws;                       // n*128: h1 / h2
    float* bufB = ws + (size_t)n * 128;     // n*128: conv outputs
    float* S = bufB + (size_t)n * 128;
    float* asrc1 = S;                       // 2n
    float* adst1 = S + 2 * (size_t)n;       // 2n
    float* asrc2 = S + 4 * (size_t)n;       // n
    float* adst2 = S + 5 * (size_t)n;       // n
    float* sums = S + 6 * (size_t)n;        // G*64
    float* cnt = sums + GRAPHS * HIDC;      // G
    int* I = (int*)(cnt + GRAPHS + 64);
    int* deg = I;                           // n
    int* rowptr = I + n;                    // n+1
    int* cursor = rowptr + n + 1;           // n
    int* bsums = cursor + n;                // ~128
    int* col = bsums + 128;                 // E

    const int nb = (n + 1023) / 1024;

    // ---- CSR build (dst-major) ----
    hipMemsetAsync(deg, 0, (size_t)n * sizeof(int), stream);
    deg_kernel<<<2048, 256, 0, stream>>>(ei, E, deg);
    scan_block<<<nb, 256, 0, stream>>>(deg, rowptr, bsums, n);
    scan_bsums<<<1, 64, 0, stream>>>(bsums, nb);
    scan_add<<<(n + 256) / 256, 256, 0, stream>>>(rowptr, bsums, cursor, n, E);
    scatter_edges<<<2048, 256, 0, stream>>>(ei, E, cursor, col);

    // ---- layer 1 ----
    dim3 g1((n + 63) / 64, 2);
    gemm_kernel<false><<<g1, 256, 0, stream>>>(x, W1, bufA, nullptr, n, 128, 128);
    alpha1_kernel<<<2048, 256, 0, stream>>>(bufA, att_src1, att_dst1, asrc1, adst1, n);
    gat_agg1<<<(n + 3) / 4, 256, 0, stream>>>(rowptr, col, bufA, asrc1, adst1, bufB, n);

    // ---- layer 2 (bias1+ReLU fused into A-load of gemm2) ----
    dim3 g2((n + 63) / 64, 1);
    gemm_kernel<true><<<g2, 256, 0, stream>>>(bufB, W2, bufA, b1, n, 128, 64);
    alpha2_kernel<<<2048, 256, 0, stream>>>(bufA, att_src2, att_dst2, asrc2, adst2, n);
    gat_agg2<<<(n + 3) / 4, 256, 0, stream>>>(rowptr, col, bufA, asrc2, adst2, bufB, n);

    // ---- pool + final linear (bias2 folded into final) ----
    hipMemsetAsync(sums, 0, (GRAPHS * HIDC + GRAPHS) * sizeof(float), stream);
    pool_kernel<<<(n + NPB - 1) / NPB, 256, 0, stream>>>(bufB, batch, sums, cnt, n);
    final_kernel<<<(GRAPHS * OUTC + 255) / 256, 256, 0, stream>>>(sums, cnt, b2, Wl, bl, out);
}

// Round 3
// 688.633 us; speedup vs baseline: 2.2804x; 1.1090x over previous
//
#include <hip/hip_runtime.h>
#include <math.h>

#define GRAPHS 100
#define HIDC 64
#define OUTC 16
#define SLOPE 0.2f

typedef unsigned short ushort_t;
typedef short bf16x8 __attribute__((ext_vector_type(8)));
typedef float f32x4 __attribute__((ext_vector_type(4)));

__device__ __forceinline__ float lrelu(float v) { return v > 0.f ? v : SLOPE * v; }
__device__ __forceinline__ void atomAddG(float* p, float v) { unsafeAtomicAdd(p, v); }
__device__ __forceinline__ float bf2f(ushort_t u) {
    unsigned int x = ((unsigned int)u) << 16;
    return __builtin_bit_cast(float, x);
}
__device__ __forceinline__ ushort_t f2bf(float f) {
    unsigned int u = __builtin_bit_cast(unsigned int, f);
    u += 0x7FFFu + ((u >> 16) & 1u);  // RNE
    return (ushort_t)(u >> 16);
}
__device__ __forceinline__ unsigned int pack2(float lo, float hi) {
    return (unsigned int)f2bf(lo) | ((unsigned int)f2bf(hi) << 16);
}

// ---------------- MFMA bf16 GEMM: C_bf16[M,N] = A[M,K] @ W_f32[K,N] ----------------
// BM=64, BN=64, BK=32. 4 waves (2x2), each 32x32 out (2x2 MFMA 16x16x32 tiles).
// LDS: As[row][k] / Bs[col][k], leading dim 40 bf16 (pad 8) -> conflict-light b128.
template <bool A_IS_BF16>
__global__ __launch_bounds__(256) void mfma_gemm(const void* __restrict__ Av,
                                                 const float* __restrict__ W,
                                                 ushort_t* __restrict__ Cbf,
                                                 int M, int K, int N) {
    __shared__ ushort_t As[64 * 40];
    __shared__ ushort_t Bs[64 * 40];
    const int tid = threadIdx.x;
    const int row0 = blockIdx.x * 64;
    const int col0 = blockIdx.y * 64;
    const int lane = tid & 63;
    const int wv = tid >> 6;
    const int wr = (wv >> 1) * 32, wc = (wv & 1) * 32;
    const int l15 = lane & 15, l4 = lane >> 4;

    const int srow = tid >> 2;
    const int skoff = (tid & 3) * 8;
    const int bc = tid & 63, bk = (tid >> 6) * 8;

    f32x4 acc[2][2] = {};

    for (int k0 = 0; k0 < K; k0 += 32) {
        // stage A tile (64 x 32 bf16)
        {
            int gr = row0 + srow;
            uint4 v = {0u, 0u, 0u, 0u};
            if (gr < M) {
                if (A_IS_BF16) {
                    const ushort_t* Ab = (const ushort_t*)Av;
                    v = *(const uint4*)(Ab + (size_t)gr * K + k0 + skoff);
                } else {
                    const float* Af = (const float*)Av;
                    const float4 a0 = *(const float4*)(Af + (size_t)gr * K + k0 + skoff);
                    const float4 a1 = *(const float4*)(Af + (size_t)gr * K + k0 + skoff + 4);
                    v.x = pack2(a0.x, a0.y);
                    v.y = pack2(a0.z, a0.w);
                    v.z = pack2(a1.x, a1.y);
                    v.w = pack2(a1.z, a1.w);
                }
            }
            *(uint4*)&As[srow * 40 + skoff] = v;
        }
        // stage B tile transposed: Bs[col][k] <- W[k0+k][col0+col]
        {
#pragma unroll
            for (int j = 0; j < 8; ++j) {
                float w = W[(size_t)(k0 + bk + j) * N + col0 + bc];
                Bs[bc * 40 + bk + j] = f2bf(w);
            }
        }
        __syncthreads();
        bf16x8 af[2], bfr[2];
#pragma unroll
        for (int mi = 0; mi < 2; ++mi)
            af[mi] = *(const bf16x8*)&As[(wr + mi * 16 + l15) * 40 + l4 * 8];
#pragma unroll
        for (int ni = 0; ni < 2; ++ni)
            bfr[ni] = *(const bf16x8*)&Bs[(wc + ni * 16 + l15) * 40 + l4 * 8];
#pragma unroll
        for (int mi = 0; mi < 2; ++mi)
#pragma unroll
            for (int ni = 0; ni < 2; ++ni)
                acc[mi][ni] = __builtin_amdgcn_mfma_f32_16x16x32_bf16(af[mi], bfr[ni],
                                                                     acc[mi][ni], 0, 0, 0);
        __syncthreads();
    }
    // epilogue: D row = (lane>>4)*4 + r, col = lane&15
#pragma unroll
    for (int mi = 0; mi < 2; ++mi)
#pragma unroll
        for (int ni = 0; ni < 2; ++ni)
#pragma unroll
            for (int r = 0; r < 4; ++r) {
                int row = row0 + wr + mi * 16 + l4 * 4 + r;
                int colg = col0 + wc + ni * 16 + l15;
                if (row < M) Cbf[(size_t)row * N + colg] = f2bf(acc[mi][ni][r]);
            }
}

// ---------------- attention coefficients (bf16 h) ----------------
// layer1: h [n,128] bf16 (head0 feats 0-63, head1 64-127)
__global__ void alpha1_kernel(const ushort_t* __restrict__ h, const float* __restrict__ att_src,
                              const float* __restrict__ att_dst, float* __restrict__ asrc,
                              float* __restrict__ adst, int n) {
    int lane = threadIdx.x & 63;
    int wid = (blockIdx.x * blockDim.x + threadIdx.x) >> 6;
    int nw = (gridDim.x * blockDim.x) >> 6;
    float as0 = att_src[2 * lane], as1 = att_src[2 * lane + 1];
    float ad0 = att_dst[2 * lane], ad1 = att_dst[2 * lane + 1];
    for (int i = wid; i < n; i += nw) {
        ushort2 v = *(const ushort2*)(h + (size_t)i * 128 + 2 * lane);
        float v0 = bf2f(v.x), v1 = bf2f(v.y);
        float s = v0 * as0 + v1 * as1;
        float d = v0 * ad0 + v1 * ad1;
#pragma unroll
        for (int off = 16; off; off >>= 1) {
            s += __shfl_xor(s, off);
            d += __shfl_xor(d, off);
        }
        if ((lane & 31) == 0) {
            int hd = lane >> 5;
            asrc[2 * i + hd] = s;
            adst[2 * i + hd] = d;
        }
    }
}

__global__ void alpha2_kernel(const ushort_t* __restrict__ h, const float* __restrict__ att_src,
                              const float* __restrict__ att_dst, float* __restrict__ asrc,
                              float* __restrict__ adst, int n) {
    int lane = threadIdx.x & 63;
    int wid = (blockIdx.x * blockDim.x + threadIdx.x) >> 6;
    int nw = (gridDim.x * blockDim.x) >> 6;
    float asc = att_src[lane], adc = att_dst[lane];
    for (int i = wid; i < n; i += nw) {
        float v = bf2f(h[(size_t)i * 64 + lane]);
        float s = v * asc, d = v * adc;
#pragma unroll
        for (int off = 32; off; off >>= 1) {
            s += __shfl_xor(s, off);
            d += __shfl_xor(d, off);
        }
        if (lane == 0) {
            asrc[i] = s;
            adst[i] = d;
        }
    }
}

// ---------------- CSR build (dst -> list of src) ----------------
__global__ void deg_kernel(const int* __restrict__ ei, int E, int* __restrict__ deg) {
    int stride = gridDim.x * blockDim.x;
    for (int e = blockIdx.x * blockDim.x + threadIdx.x; e < E; e += stride)
        atomicAdd(&deg[ei[E + e]], 1);
}

__global__ __launch_bounds__(256) void scan_block(const int* __restrict__ deg,
                                                  int* __restrict__ rp,
                                                  int* __restrict__ bsums, int n) {
    __shared__ int sh[256];
    int base = blockIdx.x * 1024;
    int t = threadIdx.x;
    int i0 = base + t * 4;
    int v0 = 0, v1 = 0, v2 = 0, v3 = 0;
    if (i0 + 3 < n) {
        int4 q = *(const int4*)(deg + i0);
        v0 = q.x; v1 = q.y; v2 = q.z; v3 = q.w;
    } else {
        if (i0 < n) v0 = deg[i0];
        if (i0 + 1 < n) v1 = deg[i0 + 1];
        if (i0 + 2 < n) v2 = deg[i0 + 2];
        if (i0 + 3 < n) v3 = deg[i0 + 3];
    }
    int tsum = v0 + v1 + v2 + v3;
    sh[t] = tsum;
    __syncthreads();
#pragma unroll
    for (int off = 1; off < 256; off <<= 1) {
        int val = (t >= off) ? sh[t - off] : 0;
        __syncthreads();
        sh[t] += val;
        __syncthreads();
    }
    if (t == 255) bsums[blockIdx.x] = sh[255];
    int p = sh[t] - tsum;
    if (i0 < n) rp[i0] = p;
    p += v0;
    if (i0 + 1 < n) rp[i0 + 1] = p;
    p += v1;
    if (i0 + 2 < n) rp[i0 + 2] = p;
    p += v2;
    if (i0 + 3 < n) rp[i0 + 3] = p;
}

__global__ void scan_bsums(int* __restrict__ bsums, int nb) {
    if (threadIdx.x == 0 && blockIdx.x == 0) {
        int acc = 0;
        for (int b = 0; b < nb; ++b) {
            int v = bsums[b];
            bsums[b] = acc;
            acc += v;
        }
    }
}

__global__ void scan_add(int* __restrict__ rp, const int* __restrict__ bsums,
                         int* __restrict__ cursor, int n, int E) {
    int idx = blockIdx.x * blockDim.x + threadIdx.x;
    if (idx < n) {
        int v = rp[idx] + bsums[idx >> 10];
        rp[idx] = v;
        cursor[idx] = v;
    }
    if (idx == n) rp[n] = E;
}

__global__ void scatter_edges(const int* __restrict__ ei, int E, int* __restrict__ cursor,
                              int* __restrict__ col) {
    int stride = gridDim.x * blockDim.x;
    for (int e = blockIdx.x * blockDim.x + threadIdx.x; e < E; e += stride) {
        int s = ei[e], d = ei[E + e];
        int pos = atomicAdd(&cursor[d], 1);
        col[pos] = s;
    }
}

// ---------------- fused GAT aggregation, 2 edges/wave-iter, bf16 gather ----------------
// layer1: h [n,128] bf16; out = relu(agg/den + b1) as bf16 [n,128]
__global__ __launch_bounds__(256) void gat_agg1(const int* __restrict__ rowptr,
                                                const int* __restrict__ col,
                                                const ushort_t* __restrict__ h,
                                                const float* __restrict__ asrc,
                                                const float* __restrict__ adst,
                                                const float* __restrict__ b1,
                                                ushort_t* __restrict__ outb, int n) {
    int i = (blockIdx.x * blockDim.x + threadIdx.x) >> 6;
    if (i >= n) return;
    int lane = threadIdx.x & 63;
    int half = lane >> 5;   // which edge of the pair
    int c = lane & 31;      // feature group: feats 4c..4c+3
    int head = c >> 4;
    float ad = adst[2 * i + head];
    float acc0 = 0.f, acc1 = 0.f, acc2 = 0.f, acc3 = 0.f, den = 0.f;
    if (half == 0) {  // self-loop term
        float w = __expf(lrelu(asrc[2 * i + head] + ad));
        ushort4 hv = *(const ushort4*)(h + (size_t)i * 128 + 4 * c);
        acc0 = bf2f(hv.x) * w; acc1 = bf2f(hv.y) * w;
        acc2 = bf2f(hv.z) * w; acc3 = bf2f(hv.w) * w;
        den = w;
    }
    int e0 = rowptr[i], end = rowptr[i + 1];
    for (int e = e0; e < end; e += 2) {
        int idx = e + half;
        bool valid = idx < end;
        int s = col[valid ? idx : e];
        float as = asrc[2 * s + head];
        float w = valid ? __expf(lrelu(as + ad)) : 0.f;
        ushort4 hv = *(const ushort4*)(h + (size_t)s * 128 + 4 * c);
        acc0 = fmaf(bf2f(hv.x), w, acc0);
        acc1 = fmaf(bf2f(hv.y), w, acc1);
        acc2 = fmaf(bf2f(hv.z), w, acc2);
        acc3 = fmaf(bf2f(hv.w), w, acc3);
        den += w;
    }
    acc0 += __shfl_xor(acc0, 32);
    acc1 += __shfl_xor(acc1, 32);
    acc2 += __shfl_xor(acc2, 32);
    acc3 += __shfl_xor(acc3, 32);
    den += __shfl_xor(den, 32);
    if (half == 0) {
        float inv = 1.f / den;
        float4 bb = *(const float4*)(b1 + 4 * c);
        float r0 = fmaf(acc0, inv, bb.x); r0 = r0 > 0.f ? r0 : 0.f;
        float r1 = fmaf(acc1, inv, bb.y); r1 = r1 > 0.f ? r1 : 0.f;
        float r2 = fmaf(acc2, inv, bb.z); r2 = r2 > 0.f ? r2 : 0.f;
        float r3 = fmaf(acc3, inv, bb.w); r3 = r3 > 0.f ? r3 : 0.f;
        ushort4 ov = {f2bf(r0), f2bf(r1), f2bf(r2), f2bf(r3)};
        *(ushort4*)(outb + (size_t)i * 128 + 4 * c) = ov;
    }
}

// layer2: h [n,64] bf16, 1 head; out fp32 [n,64]
__global__ __launch_bounds__(256) void gat_agg2(const int* __restrict__ rowptr,
                                                const int* __restrict__ col,
                                                const ushort_t* __restrict__ h,
                                                const float* __restrict__ asrc,
                                                const float* __restrict__ adst,
                                                float* __restrict__ outb, int n) {
    int i = (blockIdx.x * blockDim.x + threadIdx.x) >> 6;
    if (i >= n) return;
    int lane = threadIdx.x & 63;
    int half = lane >> 5;
    int c = lane & 31;  // feats 2c..2c+1
    float ad = adst[i];
    float acc0 = 0.f, acc1 = 0.f, den = 0.f;
    if (half == 0) {
        float w = __expf(lrelu(asrc[i] + ad));
        ushort2 hv = *(const ushort2*)(h + (size_t)i * 64 + 2 * c);
        acc0 = bf2f(hv.x) * w;
        acc1 = bf2f(hv.y) * w;
        den = w;
    }
    int e0 = rowptr[i], end = rowptr[i + 1];
    for (int e = e0; e < end; e += 2) {
        int idx = e + half;
        bool valid = idx < end;
        int s = col[valid ? idx : e];
        float as = asrc[s];
        float w = valid ? __expf(lrelu(as + ad)) : 0.f;
        ushort2 hv = *(const ushort2*)(h + (size_t)s * 64 + 2 * c);
        acc0 = fmaf(bf2f(hv.x), w, acc0);
        acc1 = fmaf(bf2f(hv.y), w, acc1);
        den += w;
    }
    acc0 += __shfl_xor(acc0, 32);
    acc1 += __shfl_xor(acc1, 32);
    den += __shfl_xor(den, 32);
    if (half == 0) {
        float inv = 1.f / den;
        float2 o = {acc0 * inv, acc1 * inv};
        *(float2*)(outb + (size_t)i * 64 + 2 * c) = o;
    }
}

// ---------------- mean pool (batch sorted) ----------------
#define NPB 256
__global__ __launch_bounds__(256) void pool_kernel(const float* __restrict__ h,
                                                   const int* __restrict__ batch,
                                                   float* __restrict__ sums,
                                                   float* __restrict__ cnt, int n) {
    __shared__ float ls[GRAPHS * HIDC];
    __shared__ float lc[GRAPHS];
    int base = blockIdx.x * NPB;
    for (int t = threadIdx.x; t < GRAPHS * HIDC; t += blockDim.x) ls[t] = 0.f;
    for (int t = threadIdx.x; t < GRAPHS; t += blockDim.x) lc[t] = 0.f;
    __syncthreads();
    int wave = threadIdx.x >> 6, lane = threadIdx.x & 63;
    int end = base + NPB < n ? base + NPB : n;
    for (int i = base + wave; i < end; i += 4) {
        int g = batch[i];
        unsafeAtomicAdd(&ls[g * HIDC + lane], h[(size_t)i * HIDC + lane]);
        if (lane == 0) unsafeAtomicAdd(&lc[g], 1.f);
    }
    __syncthreads();
    int gmin = batch[base];
    int gmax = batch[end - 1];
    int ng = gmax - gmin + 1;
    for (int t = threadIdx.x; t < ng * HIDC; t += blockDim.x) {
        int g = gmin + t / HIDC, c = t % HIDC;
        atomAddG(&sums[g * HIDC + c], ls[g * HIDC + c]);
    }
    for (int g = gmin + (int)threadIdx.x; g <= gmax; g += blockDim.x)
        atomAddG(&cnt[g], lc[g]);
}

// ---------------- final linear ----------------
__global__ void final_kernel(const float* __restrict__ sums, const float* __restrict__ cnt,
                             const float* __restrict__ b2, const float* __restrict__ Wl,
                             const float* __restrict__ bl, float* __restrict__ out) {
    int t = blockIdx.x * blockDim.x + threadIdx.x;
    if (t < GRAPHS * OUTC) {
        int g = t / OUTC, o = t % OUTC;
        float c = cnt[g];
        c = c > 1.f ? c : 1.f;
        float inv = 1.f / c;
        float acc = bl[o];
        for (int k = 0; k < HIDC; ++k)
            acc += (sums[g * HIDC + k] * inv + b2[k]) * Wl[k * OUTC + o];
        out[t] = acc;
    }
}

extern "C" void kernel_launch(void* const* d_in, const int* in_sizes, int n_in, void* d_out,
                              int out_size, void* d_ws, size_t ws_size, hipStream_t stream) {
    const float* x = (const float*)d_in[0];
    const int* ei = (const int*)d_in[1];
    const int* batch = (const int*)d_in[2];
    const float* W1 = (const float*)d_in[3];
    const float* att_src1 = (const float*)d_in[4];
    const float* att_dst1 = (const float*)d_in[5];
    const float* b1 = (const float*)d_in[6];
    const float* W2 = (const float*)d_in[7];
    const float* att_src2 = (const float*)d_in[8];
    const float* att_dst2 = (const float*)d_in[9];
    const float* b2 = (const float*)d_in[10];
    const float* Wl = (const float*)d_in[11];
    const float* bl = (const float*)d_in[12];
    float* out = (float*)d_out;

    const int n = in_sizes[2];
    const int E = in_sizes[1] / 2;

    char* p = (char*)d_ws;
    auto alloc = [&](size_t bytes) {
        char* r = p;
        p += (bytes + 255) & ~(size_t)255;
        return r;
    };
    ushort_t* h1 = (ushort_t*)alloc((size_t)n * 128 * 2);     // bf16 h layer1
    ushort_t* hrelu = (ushort_t*)alloc((size_t)n * 128 * 2);  // bf16 relu(conv1+b1)
    ushort_t* h2 = (ushort_t*)alloc((size_t)n * 64 * 2);      // bf16 h layer2
    float* conv2 = (float*)alloc((size_t)n * 64 * 4);         // fp32 conv2 out
    float* asrc1 = (float*)alloc((size_t)n * 2 * 4);
    float* adst1 = (float*)alloc((size_t)n * 2 * 4);
    float* asrc2 = (float*)alloc((size_t)n * 4);
    float* adst2 = (float*)alloc((size_t)n * 4);
    float* sums = (float*)alloc(GRAPHS * HIDC * 4);
    float* cnt = (float*)alloc(GRAPHS * 4);
    int* deg = (int*)alloc((size_t)n * 4);
    int* rowptr = (int*)alloc(((size_t)n + 1) * 4);
    int* cursor = (int*)alloc((size_t)n * 4);
    int* bsums = (int*)alloc(256 * 4);
    int* col = (int*)alloc((size_t)E * 4);

    const int nb = (n + 1023) / 1024;
    const int gblk = (n + 63) / 64;

    // ---- CSR build (dst-major) ----
    hipMemsetAsync(deg, 0, (size_t)n * sizeof(int), stream);
    deg_kernel<<<2048, 256, 0, stream>>>(ei, E, deg);
    scan_block<<<nb, 256, 0, stream>>>(deg, rowptr, bsums, n);
    scan_bsums<<<1, 64, 0, stream>>>(bsums, nb);
    scan_add<<<(n + 256) / 256, 256, 0, stream>>>(rowptr, bsums, cursor, n, E);
    scatter_edges<<<2048, 256, 0, stream>>>(ei, E, cursor, col);

    // ---- layer 1 ----
    mfma_gemm<false><<<dim3(gblk, 2), 256, 0, stream>>>(x, W1, h1, n, 128, 128);
    alpha1_kernel<<<2048, 256, 0, stream>>>(h1, att_src1, att_dst1, asrc1, adst1, n);
    gat_agg1<<<(n + 3) / 4, 256, 0, stream>>>(rowptr, col, h1, asrc1, adst1, b1, hrelu, n);

    // ---- layer 2 ----
    mfma_gemm<true><<<dim3(gblk, 1), 256, 0, stream>>>(hrelu, W2, h2, n, 128, 64);
    alpha2_kernel<<<2048, 256, 0, stream>>>(h2, att_src2, att_dst2, asrc2, adst2, n);
    gat_agg2<<<(n + 3) / 4, 256, 0, stream>>>(rowptr, col, h2, asrc2, adst2, conv2, n);

    // ---- pool + final (b2 folded into final) ----
    hipMemsetAsync(sums, 0, (GRAPHS * HIDC + GRAPHS) * sizeof(float), stream);
    pool_kernel<<<(n + NPB - 1) / NPB, 256, 0, stream>>>(conv2, batch, sums, cnt, n);
    final_kernel<<<(GRAPHS * OUTC + 255) / 256, 256, 0, stream>>>(sums, cnt, b2, Wl, bl, out);
}

// Round 5
// 514.300 us; speedup vs baseline: 3.0534x; 1.3390x over previous
//
#include <hip/hip_runtime.h>
#include <math.h>

#define GRAPHS 100
#define HIDC 64
#define OUTC 16
#define SLOPE 0.2f

typedef unsigned short ushort_t;
typedef short bf16x8 __attribute__((ext_vector_type(8)));
typedef float f32x4 __attribute__((ext_vector_type(4)));
typedef ushort_t u16x8 __attribute__((ext_vector_type(8)));
typedef ushort_t u16x4 __attribute__((ext_vector_type(4)));

__device__ __forceinline__ float lrelu(float v) { return v > 0.f ? v : SLOPE * v; }
__device__ __forceinline__ void atomAddG(float* p, float v) { unsafeAtomicAdd(p, v); }
__device__ __forceinline__ float bf2f(ushort_t u) {
    unsigned int x = ((unsigned int)u) << 16;
    return __builtin_bit_cast(float, x);
}
__device__ __forceinline__ ushort_t f2bf(float f) {
    unsigned int u = __builtin_bit_cast(unsigned int, f);
    u += 0x7FFFu + ((u >> 16) & 1u);  // RNE
    return (ushort_t)(u >> 16);
}
__device__ __forceinline__ unsigned int pack2(float lo, float hi) {
    return (unsigned int)f2bf(lo) | ((unsigned int)f2bf(hi) << 16);
}

// ---------------- MFMA bf16 GEMM: C_bf16[M,N] = A[M,K] @ W_f32[K,N] ----------------
template <bool A_IS_BF16>
__global__ __launch_bounds__(256) void mfma_gemm(const void* __restrict__ Av,
                                                 const float* __restrict__ W,
                                                 ushort_t* __restrict__ Cbf,
                                                 int M, int K, int N) {
    __shared__ ushort_t As[64 * 40];
    __shared__ ushort_t Bs[64 * 40];
    const int tid = threadIdx.x;
    const int row0 = blockIdx.x * 64;
    const int col0 = blockIdx.y * 64;
    const int lane = tid & 63;
    const int wv = tid >> 6;
    const int wr = (wv >> 1) * 32, wc = (wv & 1) * 32;
    const int l15 = lane & 15, l4 = lane >> 4;

    const int srow = tid >> 2;
    const int skoff = (tid & 3) * 8;
    const int bc = tid & 63, bk = (tid >> 6) * 8;

    f32x4 acc[2][2] = {};

    for (int k0 = 0; k0 < K; k0 += 32) {
        {
            int gr = row0 + srow;
            uint4 v = {0u, 0u, 0u, 0u};
            if (gr < M) {
                if (A_IS_BF16) {
                    const ushort_t* Ab = (const ushort_t*)Av;
                    v = *(const uint4*)(Ab + (size_t)gr * K + k0 + skoff);
                } else {
                    const float* Af = (const float*)Av;
                    const float4 a0 = *(const float4*)(Af + (size_t)gr * K + k0 + skoff);
                    const float4 a1 = *(const float4*)(Af + (size_t)gr * K + k0 + skoff + 4);
                    v.x = pack2(a0.x, a0.y);
                    v.y = pack2(a0.z, a0.w);
                    v.z = pack2(a1.x, a1.y);
                    v.w = pack2(a1.z, a1.w);
                }
            }
            *(uint4*)&As[srow * 40 + skoff] = v;
        }
        {
#pragma unroll
            for (int j = 0; j < 8; ++j) {
                float w = W[(size_t)(k0 + bk + j) * N + col0 + bc];
                Bs[bc * 40 + bk + j] = f2bf(w);
            }
        }
        __syncthreads();
        bf16x8 af[2], bfr[2];
#pragma unroll
        for (int mi = 0; mi < 2; ++mi)
            af[mi] = *(const bf16x8*)&As[(wr + mi * 16 + l15) * 40 + l4 * 8];
#pragma unroll
        for (int ni = 0; ni < 2; ++ni)
            bfr[ni] = *(const bf16x8*)&Bs[(wc + ni * 16 + l15) * 40 + l4 * 8];
#pragma unroll
        for (int mi = 0; mi < 2; ++mi)
#pragma unroll
            for (int ni = 0; ni < 2; ++ni)
                acc[mi][ni] = __builtin_amdgcn_mfma_f32_16x16x32_bf16(af[mi], bfr[ni],
                                                                     acc[mi][ni], 0, 0, 0);
        __syncthreads();
    }
#pragma unroll
    for (int mi = 0; mi < 2; ++mi)
#pragma unroll
        for (int ni = 0; ni < 2; ++ni)
#pragma unroll
            for (int r = 0; r < 4; ++r) {
                int row = row0 + wr + mi * 16 + l4 * 4 + r;
                int colg = col0 + wc + ni * 16 + l15;
                if (row < M) Cbf[(size_t)row * N + colg] = f2bf(acc[mi][ni][r]);
            }
}

// ---------------- attention coefficients (bf16 h) ----------------
__global__ void alpha1_kernel(const ushort_t* __restrict__ h, const float* __restrict__ att_src,
                              const float* __restrict__ att_dst, float* __restrict__ asrc,
                              float* __restrict__ adst, int n) {
    int lane = threadIdx.x & 63;
    int wid = (blockIdx.x * blockDim.x + threadIdx.x) >> 6;
    int nw = (gridDim.x * blockDim.x) >> 6;
    float as0 = att_src[2 * lane], as1 = att_src[2 * lane + 1];
    float ad0 = att_dst[2 * lane], ad1 = att_dst[2 * lane + 1];
    for (int i = wid; i < n; i += nw) {
        ushort2 v = *(const ushort2*)(h + (size_t)i * 128 + 2 * lane);
        float v0 = bf2f(v.x), v1 = bf2f(v.y);
        float s = v0 * as0 + v1 * as1;
        float d = v0 * ad0 + v1 * ad1;
#pragma unroll
        for (int off = 16; off; off >>= 1) {
            s += __shfl_xor(s, off);
            d += __shfl_xor(d, off);
        }
        if ((lane & 31) == 0) {
            int hd = lane >> 5;
            asrc[2 * i + hd] = s;
            adst[2 * i + hd] = d;
        }
    }
}

__global__ void alpha2_kernel(const ushort_t* __restrict__ h, const float* __restrict__ att_src,
                              const float* __restrict__ att_dst, float* __restrict__ asrc,
                              float* __restrict__ adst, int n) {
    int lane = threadIdx.x & 63;
    int wid = (blockIdx.x * blockDim.x + threadIdx.x) >> 6;
    int nw = (gridDim.x * blockDim.x) >> 6;
    float asc = att_src[lane], adc = att_dst[lane];
    for (int i = wid; i < n; i += nw) {
        float v = bf2f(h[(size_t)i * 64 + lane]);
        float s = v * asc, d = v * adc;
#pragma unroll
        for (int off = 32; off; off >>= 1) {
            s += __shfl_xor(s, off);
            d += __shfl_xor(d, off);
        }
        if (lane == 0) {
            asrc[i] = s;
            adst[i] = d;
        }
    }
}

// ---------------- CSR build (dst -> list of src) ----------------
__global__ void deg_kernel(const int* __restrict__ ei, int E, int* __restrict__ deg) {
    int stride = gridDim.x * blockDim.x;
    for (int e = blockIdx.x * blockDim.x + threadIdx.x; e < E; e += stride)
        atomicAdd(&deg[ei[E + e]], 1);
}

__global__ __launch_bounds__(256) void scan_block(const int* __restrict__ deg,
                                                  int* __restrict__ rp,
                                                  int* __restrict__ bsums, int n) {
    __shared__ int sh[256];
    int base = blockIdx.x * 1024;
    int t = threadIdx.x;
    int i0 = base + t * 4;
    int v0 = 0, v1 = 0, v2 = 0, v3 = 0;
    if (i0 + 3 < n) {
        int4 q = *(const int4*)(deg + i0);
        v0 = q.x; v1 = q.y; v2 = q.z; v3 = q.w;
    } else {
        if (i0 < n) v0 = deg[i0];
        if (i0 + 1 < n) v1 = deg[i0 + 1];
        if (i0 + 2 < n) v2 = deg[i0 + 2];
        if (i0 + 3 < n) v3 = deg[i0 + 3];
    }
    int tsum = v0 + v1 + v2 + v3;
    sh[t] = tsum;
    __syncthreads();
#pragma unroll
    for (int off = 1; off < 256; off <<= 1) {
        int val = (t >= off) ? sh[t - off] : 0;
        __syncthreads();
        sh[t] += val;
        __syncthreads();
    }
    if (t == 255) bsums[blockIdx.x] = sh[255];
    int p = sh[t] - tsum;
    if (i0 < n) rp[i0] = p;
    p += v0;
    if (i0 + 1 < n) rp[i0 + 1] = p;
    p += v1;
    if (i0 + 2 < n) rp[i0 + 2] = p;
    p += v2;
    if (i0 + 3 < n) rp[i0 + 3] = p;
}

__global__ void scan_bsums(int* __restrict__ bsums, int nb) {
    if (threadIdx.x == 0 && blockIdx.x == 0) {
        int acc = 0;
        for (int b = 0; b < nb; ++b) {
            int v = bsums[b];
            bsums[b] = acc;
            acc += v;
        }
    }
}

__global__ void scan_add(int* __restrict__ rp, const int* __restrict__ bsums,
                         int* __restrict__ cursor, int n, int E) {
    int idx = blockIdx.x * blockDim.x + threadIdx.x;
    if (idx < n) {
        int v = rp[idx] + bsums[idx >> 10];
        rp[idx] = v;
        cursor[idx] = v;
    }
    if (idx == n) rp[n] = E;
}

// dst-range-filtered scatter: pass p only writes col[rowptr[lo]..rowptr[hi]) -> L2-resident window
__global__ void scatter_pass(const int* __restrict__ ei, int E, int* __restrict__ cursor,
                             int* __restrict__ col, int lo, int hi) {
    int stride = gridDim.x * blockDim.x;
    for (int e = blockIdx.x * blockDim.x + threadIdx.x; e < E; e += stride) {
        int d = ei[E + e];
        if (d >= lo && d < hi) {
            int pos = atomicAdd(&cursor[d], 1);
            col[pos] = ei[e];
        }
    }
}

// ---------------- fused GAT aggregation: 16-lane groups, 8 edges in flight ----------------
// layer1: h [n,128] bf16 (256B row = 16 lanes x 16B); out = relu(agg/den + b1) bf16
__global__ __launch_bounds__(256) void gat_agg1(const int* __restrict__ rowptr,
                                                const int* __restrict__ col,
                                                const ushort_t* __restrict__ h,
                                                const float* __restrict__ asrc,
                                                const float* __restrict__ adst,
                                                const float* __restrict__ b1,
                                                ushort_t* __restrict__ outb, int n) {
    int i = (blockIdx.x * blockDim.x + threadIdx.x) >> 6;
    if (i >= n) return;
    int lane = threadIdx.x & 63;
    int grp = lane >> 4, c = lane & 15;  // feats 8c..8c+7, head = c>>3
    int head = c >> 3;
    float ad = adst[2 * i + head];
    const u16x8* h8 = (const u16x8*)h;  // row = 16 u16x8
    float acc[8] = {};
    float den = 0.f;
    if (grp == 0) {  // self-loop
        float w = __expf(lrelu(asrc[2 * i + head] + ad));
        u16x8 hv = h8[(size_t)i * 16 + c];
#pragma unroll
        for (int j = 0; j < 8; ++j) acc[j] = bf2f(hv[j]) * w;
        den = w;
    }
    int e0 = rowptr[i], end = rowptr[i + 1];
    for (int e = e0; e < end; e += 8) {
        int iA = e + grp, iB = e + 4 + grp;
        bool vA = iA < end, vB = iB < end;
        int sA = col[vA ? iA : e0];
        int sB = col[vB ? iB : e0];
        float asA = asrc[2 * sA + head];
        float asB = asrc[2 * sB + head];
        u16x8 hA = h8[(size_t)sA * 16 + c];
        u16x8 hB = h8[(size_t)sB * 16 + c];
        float wA = vA ? __expf(lrelu(asA + ad)) : 0.f;
        float wB = vB ? __expf(lrelu(asB + ad)) : 0.f;
#pragma unroll
        for (int j = 0; j < 8; ++j) acc[j] = fmaf(bf2f(hA[j]), wA, acc[j]);
#pragma unroll
        for (int j = 0; j < 8; ++j) acc[j] = fmaf(bf2f(hB[j]), wB, acc[j]);
        den += wA + wB;
    }
#pragma unroll
    for (int j = 0; j < 8; ++j) {
        acc[j] += __shfl_xor(acc[j], 16);
        acc[j] += __shfl_xor(acc[j], 32);
    }
    den += __shfl_xor(den, 16);
    den += __shfl_xor(den, 32);
    if (grp == 0) {
        float inv = 1.f / den;
        u16x8 ov;
#pragma unroll
        for (int j = 0; j < 8; ++j) {
            float r = fmaf(acc[j], inv, b1[8 * c + j]);
            r = r > 0.f ? r : 0.f;
            ov[j] = f2bf(r);
        }
        *((u16x8*)outb + (size_t)i * 16 + c) = ov;
    }
}

// layer2: h [n,64] bf16 (128B row = 16 lanes x 8B); out fp32 [n,64]
__global__ __launch_bounds__(256) void gat_agg2(const int* __restrict__ rowptr,
                                                const int* __restrict__ col,
                                                const ushort_t* __restrict__ h,
                                                const float* __restrict__ asrc,
                                                const float* __restrict__ adst,
                                                float* __restrict__ outb, int n) {
    int i = (blockIdx.x * blockDim.x + threadIdx.x) >> 6;
    if (i >= n) return;
    int lane = threadIdx.x & 63;
    int grp = lane >> 4, c = lane & 15;  // feats 4c..4c+3
    float ad = adst[i];
    const u16x4* h4 = (const u16x4*)h;  // row = 16 u16x4
    float acc[4] = {};
    float den = 0.f;
    if (grp == 0) {
        float w = __expf(lrelu(asrc[i] + ad));
        u16x4 hv = h4[(size_t)i * 16 + c];
#pragma unroll
        for (int j = 0; j < 4; ++j) acc[j] = bf2f(hv[j]) * w;
        den = w;
    }
    int e0 = rowptr[i], end = rowptr[i + 1];
    for (int e = e0; e < end; e += 8) {
        int iA = e + grp, iB = e + 4 + grp;
        bool vA = iA < end, vB = iB < end;
        int sA = col[vA ? iA : e0];
        int sB = col[vB ? iB : e0];
        float asA = asrc[sA];
        float asB = asrc[sB];
        u16x4 hA = h4[(size_t)sA * 16 + c];
        u16x4 hB = h4[(size_t)sB * 16 + c];
        float wA = vA ? __expf(lrelu(asA + ad)) : 0.f;
        float wB = vB ? __expf(lrelu(asB + ad)) : 0.f;
#pragma unroll
        for (int j = 0; j < 4; ++j) acc[j] = fmaf(bf2f(hA[j]), wA, acc[j]);
#pragma unroll
        for (int j = 0; j < 4; ++j) acc[j] = fmaf(bf2f(hB[j]), wB, acc[j]);
        den += wA + wB;
    }
#pragma unroll
    for (int j = 0; j < 4; ++j) {
        acc[j] += __shfl_xor(acc[j], 16);
        acc[j] += __shfl_xor(acc[j], 32);
    }
    den += __shfl_xor(den, 16);
    den += __shfl_xor(den, 32);
    if (grp == 0) {
        float inv = 1.f / den;
        float4 o = {acc[0] * inv, acc[1] * inv, acc[2] * inv, acc[3] * inv};
        *((float4*)outb + (size_t)i * 16 + c) = o;
    }
}

// ---------------- mean pool (batch sorted) ----------------
#define NPB 256
__global__ __launch_bounds__(256) void pool_kernel(const float* __restrict__ h,
                                                   const int* __restrict__ batch,
                                                   float* __restrict__ sums,
                                                   float* __restrict__ cnt, int n) {
    __shared__ float ls[GRAPHS * HIDC];
    __shared__ float lc[GRAPHS];
    int base = blockIdx.x * NPB;
    for (int t = threadIdx.x; t < GRAPHS * HIDC; t += blockDim.x) ls[t] = 0.f;
    for (int t = threadIdx.x; t < GRAPHS; t += blockDim.x) lc[t] = 0.f;
    __syncthreads();
    int wave = threadIdx.x >> 6, lane = threadIdx.x & 63;
    int end = base + NPB < n ? base + NPB : n;
    for (int i = base + wave; i < end; i += 4) {
        int g = batch[i];
        unsafeAtomicAdd(&ls[g * HIDC + lane], h[(size_t)i * HIDC + lane]);
        if (lane == 0) unsafeAtomicAdd(&lc[g], 1.f);
    }
    __syncthreads();
    int gmin = batch[base];
    int gmax = batch[end - 1];
    int ng = gmax - gmin + 1;
    for (int t = threadIdx.x; t < ng * HIDC; t += blockDim.x) {
        int g = gmin + t / HIDC, c = t % HIDC;
        atomAddG(&sums[g * HIDC + c], ls[g * HIDC + c]);
    }
    for (int g = gmin + (int)threadIdx.x; g <= gmax; g += blockDim.x)
        atomAddG(&cnt[g], lc[g]);
}

// ---------------- final linear ----------------
__global__ void final_kernel(const float* __restrict__ sums, const float* __restrict__ cnt,
                             const float* __restrict__ b2, const float* __restrict__ Wl,
                             const float* __restrict__ bl, float* __restrict__ out) {
    int t = blockIdx.x * blockDim.x + threadIdx.x;
    if (t < GRAPHS * OUTC) {
        int g = t / OUTC, o = t % OUTC;
        float c = cnt[g];
        c = c > 1.f ? c : 1.f;
        float inv = 1.f / c;
        float acc = bl[o];
        for (int k = 0; k < HIDC; ++k)
            acc += (sums[g * HIDC + k] * inv + b2[k]) * Wl[k * OUTC + o];
        out[t] = acc;
    }
}

extern "C" void kernel_launch(void* const* d_in, const int* in_sizes, int n_in, void* d_out,
                              int out_size, void* d_ws, size_t ws_size, hipStream_t stream) {
    const float* x = (const float*)d_in[0];
    const int* ei = (const int*)d_in[1];
    const int* batch = (const int*)d_in[2];
    const float* W1 = (const float*)d_in[3];
    const float* att_src1 = (const float*)d_in[4];
    const float* att_dst1 = (const float*)d_in[5];
    const float* b1 = (const float*)d_in[6];
    const float* W2 = (const float*)d_in[7];
    const float* att_src2 = (const float*)d_in[8];
    const float* att_dst2 = (const float*)d_in[9];
    const float* b2 = (const float*)d_in[10];
    const float* Wl = (const float*)d_in[11];
    const float* bl = (const float*)d_in[12];
    float* out = (float*)d_out;

    const int n = in_sizes[2];
    const int E = in_sizes[1] / 2;

    char* p = (char*)d_ws;
    auto alloc = [&](size_t bytes) {
        char* r = p;
        p += (bytes + 255) & ~(size_t)255;
        return r;
    };
    ushort_t* h1 = (ushort_t*)alloc((size_t)n * 128 * 2);
    ushort_t* hrelu = (ushort_t*)alloc((size_t)n * 128 * 2);
    ushort_t* h2 = (ushort_t*)alloc((size_t)n * 64 * 2);
    float* conv2 = (float*)alloc((size_t)n * 64 * 4);
    float* asrc1 = (float*)alloc((size_t)n * 2 * 4);
    float* adst1 = (float*)alloc((size_t)n * 2 * 4);
    float* asrc2 = (float*)alloc((size_t)n * 4);
    float* adst2 = (float*)alloc((size_t)n * 4);
    float* sums = (float*)alloc(GRAPHS * HIDC * 4);
    float* cnt = (float*)alloc(GRAPHS * 4);
    int* deg = (int*)alloc((size_t)n * 4);
    int* rowptr = (int*)alloc(((size_t)n + 1) * 4);
    int* cursor = (int*)alloc((size_t)n * 4);
    int* bsums = (int*)alloc(256 * 4);
    int* col = (int*)alloc((size_t)E * 4);

    const int nb = (n + 1023) / 1024;
    const int gblk = (n + 63) / 64;

    // ---- CSR build (dst-major) ----
    hipMemsetAsync(deg, 0, (size_t)n * sizeof(int), stream);
    deg_kernel<<<2048, 256, 0, stream>>>(ei, E, deg);
    scan_block<<<nb, 256, 0, stream>>>(deg, rowptr, bsums, n);
    scan_bsums<<<1, 64, 0, stream>>>(bsums, nb);
    scan_add<<<(n + 256) / 256, 256, 0, stream>>>(rowptr, bsums, cursor, n, E);
    const int NPASS = 4;
    for (int pp = 0; pp < NPASS; ++pp) {
        int lo = (int)((long long)n * pp / NPASS);
        int hi = (int)((long long)n * (pp + 1) / NPASS);
        scatter_pass<<<2048, 256, 0, stream>>>(ei, E, cursor, col, lo, hi);
    }

    // ---- layer 1 ----
    mfma_gemm<false><<<dim3(gblk, 2), 256, 0, stream>>>(x, W1, h1, n, 128, 128);
    alpha1_kernel<<<2048, 256, 0, stream>>>(h1, att_src1, att_dst1, asrc1, adst1, n);
    gat_agg1<<<(n + 3) / 4, 256, 0, stream>>>(rowptr, col, h1, asrc1, adst1, b1, hrelu, n);

    // ---- layer 2 ----
    mfma_gemm<true><<<dim3(gblk, 1), 256, 0, stream>>>(hrelu, W2, h2, n, 128, 64);
    alpha2_kernel<<<2048, 256, 0, stream>>>(h2, att_src2, att_dst2, asrc2, adst2, n);
    gat_agg2<<<(n + 3) / 4, 256, 0, stream>>>(rowptr, col, h2, asrc2, adst2, conv2, n);

    // ---- pool + final (b2 folded into final) ----
    hipMemsetAsync(sums, 0, (GRAPHS * HIDC + GRAPHS) * sizeof(float), stream);
    pool_kernel<<<(n + NPB - 1) / NPB, 256, 0, stream>>>(conv2, batch, sums, cnt, n);
    final_kernel<<<(GRAPHS * OUTC + 255) / 256, 256, 0, stream>>>(sums, cnt, b2, Wl, bl, out);
}

// Round 7
// 396.441 us; speedup vs baseline: 3.9612x; 1.2973x over previous
//
#include <hip/hip_runtime.h>
#include <math.h>

#define GRAPHS 100
#define HIDC 64
#define OUTC 16
#define SLOPE 0.2f
#define BSHIFT 8
#define MAXNB 512
#define BKT_CAP 10240

typedef unsigned short ushort_t;
typedef short bf16x8 __attribute__((ext_vector_type(8)));
typedef float f32x4 __attribute__((ext_vector_type(4)));
typedef ushort_t u16x8 __attribute__((ext_vector_type(8)));
typedef ushort_t u16x4 __attribute__((ext_vector_type(4)));

__device__ __forceinline__ float lrelu(float v) { return v > 0.f ? v : SLOPE * v; }
__device__ __forceinline__ void atomAddG(float* p, float v) { unsafeAtomicAdd(p, v); }
__device__ __forceinline__ float bf2f(ushort_t u) {
    unsigned int x = ((unsigned int)u) << 16;
    return __builtin_bit_cast(float, x);
}
__device__ __forceinline__ ushort_t f2bf(float f) {
    unsigned int u = __builtin_bit_cast(unsigned int, f);
    u += 0x7FFFu + ((u >> 16) & 1u);  // RNE
    return (ushort_t)(u >> 16);
}
__device__ __forceinline__ unsigned int pack2(float lo, float hi) {
    return (unsigned int)f2bf(lo) | ((unsigned int)f2bf(hi) << 16);
}

// ---------------- MFMA bf16 GEMM: C_bf16[M,N] = A[M,K] @ W_f32[K,N] ----------------
template <bool A_IS_BF16>
__global__ __launch_bounds__(256) void mfma_gemm(const void* __restrict__ Av,
                                                 const float* __restrict__ W,
                                                 ushort_t* __restrict__ Cbf,
                                                 int M, int K, int N) {
    __shared__ ushort_t As[64 * 40];
    __shared__ ushort_t Bs[64 * 40];
    const int tid = threadIdx.x;
    const int row0 = blockIdx.x * 64;
    const int col0 = blockIdx.y * 64;
    const int lane = tid & 63;
    const int wv = tid >> 6;
    const int wr = (wv >> 1) * 32, wc = (wv & 1) * 32;
    const int l15 = lane & 15, l4 = lane >> 4;

    const int srow = tid >> 2;
    const int skoff = (tid & 3) * 8;
    const int bc = tid & 63, bk = (tid >> 6) * 8;

    f32x4 acc[2][2] = {};

    for (int k0 = 0; k0 < K; k0 += 32) {
        {
            int gr = row0 + srow;
            uint4 v = {0u, 0u, 0u, 0u};
            if (gr < M) {
                if (A_IS_BF16) {
                    const ushort_t* Ab = (const ushort_t*)Av;
                    v = *(const uint4*)(Ab + (size_t)gr * K + k0 + skoff);
                } else {
                    const float* Af = (const float*)Av;
                    const float4 a0 = *(const float4*)(Af + (size_t)gr * K + k0 + skoff);
                    const float4 a1 = *(const float4*)(Af + (size_t)gr * K + k0 + skoff + 4);
                    v.x = pack2(a0.x, a0.y);
                    v.y = pack2(a0.z, a0.w);
                    v.z = pack2(a1.x, a1.y);
                    v.w = pack2(a1.z, a1.w);
                }
            }
            *(uint4*)&As[srow * 40 + skoff] = v;
        }
        {
#pragma unroll
            for (int j = 0; j < 8; ++j) {
                float w = W[(size_t)(k0 + bk + j) * N + col0 + bc];
                Bs[bc * 40 + bk + j] = f2bf(w);
            }
        }
        __syncthreads();
        bf16x8 af[2], bfr[2];
#pragma unroll
        for (int mi = 0; mi < 2; ++mi)
            af[mi] = *(const bf16x8*)&As[(wr + mi * 16 + l15) * 40 + l4 * 8];
#pragma unroll
        for (int ni = 0; ni < 2; ++ni)
            bfr[ni] = *(const bf16x8*)&Bs[(wc + ni * 16 + l15) * 40 + l4 * 8];
#pragma unroll
        for (int mi = 0; mi < 2; ++mi)
#pragma unroll
            for (int ni = 0; ni < 2; ++ni)
                acc[mi][ni] = __builtin_amdgcn_mfma_f32_16x16x32_bf16(af[mi], bfr[ni],
                                                                     acc[mi][ni], 0, 0, 0);
        __syncthreads();
    }
#pragma unroll
    for (int mi = 0; mi < 2; ++mi)
#pragma unroll
        for (int ni = 0; ni < 2; ++ni)
#pragma unroll
            for (int r = 0; r < 4; ++r) {
                int row = row0 + wr + mi * 16 + l4 * 4 + r;
                int colg = col0 + wc + ni * 16 + l15;
                if (row < M) Cbf[(size_t)row * N + colg] = f2bf(acc[mi][ni][r]);
            }
}

// ---------------- attention coefficients (bf16 h) ----------------
__global__ void alpha1_kernel(const ushort_t* __restrict__ h, const float* __restrict__ att_src,
                              const float* __restrict__ att_dst, float* __restrict__ asrc,
                              float* __restrict__ adst, int n) {
    int lane = threadIdx.x & 63;
    int wid = (blockIdx.x * blockDim.x + threadIdx.x) >> 6;
    int nw = (gridDim.x * blockDim.x) >> 6;
    float as0 = att_src[2 * lane], as1 = att_src[2 * lane + 1];
    float ad0 = att_dst[2 * lane], ad1 = att_dst[2 * lane + 1];
    for (int i = wid; i < n; i += nw) {
        ushort2 v = *(const ushort2*)(h + (size_t)i * 128 + 2 * lane);
        float v0 = bf2f(v.x), v1 = bf2f(v.y);
        float s = v0 * as0 + v1 * as1;
        float d = v0 * ad0 + v1 * ad1;
#pragma unroll
        for (int off = 16; off; off >>= 1) {
            s += __shfl_xor(s, off);
            d += __shfl_xor(d, off);
        }
        if ((lane & 31) == 0) {
            int hd = lane >> 5;
            asrc[2 * i + hd] = s;
            adst[2 * i + hd] = d;
        }
    }
}

__global__ void alpha2_kernel(const ushort_t* __restrict__ h, const float* __restrict__ att_src,
                              const float* __restrict__ att_dst, float* __restrict__ asrc,
                              float* __restrict__ adst, int n) {
    int lane = threadIdx.x & 63;
    int wid = (blockIdx.x * blockDim.x + threadIdx.x) >> 6;
    int nw = (gridDim.x * blockDim.x) >> 6;
    float asc = att_src[lane], adc = att_dst[lane];
    for (int i = wid; i < n; i += nw) {
        float v = bf2f(h[(size_t)i * 64 + lane]);
        float s = v * asc, d = v * adc;
#pragma unroll
        for (int off = 32; off; off >>= 1) {
            s += __shfl_xor(s, off);
            d += __shfl_xor(d, off);
        }
        if (lane == 0) {
            asrc[i] = s;
            adst[i] = d;
        }
    }
}

// ---------------- bucket-sort CSR build (dst -> list of src), no global random atomics ----
// Pass A: global per-bucket counts via LDS histograms
__global__ __launch_bounds__(256) void bucket_hist(const int* __restrict__ ei, int E,
                                                   int* __restrict__ bcnt, int NB) {
    __shared__ int h[MAXNB];
    for (int t = threadIdx.x; t < NB; t += 256) h[t] = 0;
    __syncthreads();
    int chunk = (E + gridDim.x - 1) / gridDim.x;
    int e0 = blockIdx.x * chunk;
    int e1 = e0 + chunk < E ? e0 + chunk : E;
    for (int e = e0 + threadIdx.x; e < e1; e += 256)
        atomicAdd(&h[ei[E + e] >> BSHIFT], 1);
    __syncthreads();
    for (int t = threadIdx.x; t < NB; t += 256)
        if (h[t]) atomicAdd(&bcnt[t], h[t]);
}

// Pass B: scan bucket counts -> bases + cursors (single block)
__global__ __launch_bounds__(512) void bucket_scan(const int* __restrict__ bcnt,
                                                   int* __restrict__ bbase,
                                                   int* __restrict__ bcursor,
                                                   int* __restrict__ rowptr,
                                                   int NB, int n, int E) {
    __shared__ int sh[512];
    int t = threadIdx.x;
    int v = (t < NB) ? bcnt[t] : 0;
    sh[t] = v;
    __syncthreads();
#pragma unroll
    for (int off = 1; off < 512; off <<= 1) {
        int val = (t >= off) ? sh[t - off] : 0;
        __syncthreads();
        sh[t] += val;
        __syncthreads();
    }
    if (t < NB) {
        int base = sh[t] - v;
        bbase[t] = base;
        bcursor[t] = base;
    }
    if (t == 0) {
        bbase[NB] = E;
        rowptr[n] = E;
    }
}

// Pass C: scatter edges into bucket regions; block reserves per-bucket chunks (coalesced-ish runs)
__global__ __launch_bounds__(256) void bucket_scatter(const int* __restrict__ ei, int E,
                                                      int* __restrict__ bcursor,
                                                      unsigned int* __restrict__ ebuf, int NB) {
    __shared__ int h[MAXNB];
    __shared__ int lbase[MAXNB];
    for (int t = threadIdx.x; t < NB; t += 256) h[t] = 0;
    __syncthreads();
    int chunk = (E + gridDim.x - 1) / gridDim.x;
    int e0 = blockIdx.x * chunk;
    int e1 = e0 + chunk < E ? e0 + chunk : E;
    for (int e = e0 + threadIdx.x; e < e1; e += 256)
        atomicAdd(&h[ei[E + e] >> BSHIFT], 1);
    __syncthreads();
    for (int t = threadIdx.x; t < NB; t += 256) {
        int c = h[t];
        lbase[t] = c ? atomicAdd(&bcursor[t], c) : 0;
        h[t] = 0;  // reuse as running cursor
    }
    __syncthreads();
    for (int e = e0 + threadIdx.x; e < e1; e += 256) {
        int d = ei[E + e];
        int s = ei[e];
        int b = d >> BSHIFT;
        int off = atomicAdd(&h[b], 1);
        ebuf[lbase[b] + off] = (unsigned)s | ((unsigned)(d & ((1 << BSHIFT) - 1)) << 24);
    }
}

// Pass D: per-bucket LDS counting-sort by local dst; writes rowptr + sorted col
__global__ __launch_bounds__(256) void bucket_build(const unsigned int* __restrict__ ebuf,
                                                    const int* __restrict__ bbase,
                                                    int* __restrict__ rowptr,
                                                    int* __restrict__ col, int n) {
    __shared__ int hist[256];
    __shared__ int curs[256];
    __shared__ int sh[256];
    __shared__ int lsrc[BKT_CAP];
    int b = blockIdx.x;
    int e0 = bbase[b], e1 = bbase[b + 1];
    int cnt = e1 - e0;
    int t = threadIdx.x;
    hist[t] = 0;
    __syncthreads();
    for (int k = t; k < cnt; k += 256) atomicAdd(&hist[ebuf[e0 + k] >> 24], 1);
    __syncthreads();
    int v = hist[t];
    sh[t] = v;
    __syncthreads();
#pragma unroll
    for (int off = 1; off < 256; off <<= 1) {
        int val = (t >= off) ? sh[t - off] : 0;
        __syncthreads();
        sh[t] += val;
        __syncthreads();
    }
    int ex = sh[t] - v;  // exclusive prefix
    curs[t] = ex;
    int node = (b << BSHIFT) + t;
    if (node < n) rowptr[node] = e0 + ex;
    __syncthreads();
    for (int k = t; k < cnt; k += 256) {
        unsigned pk = ebuf[e0 + k];
        int ld = pk >> 24;
        int off = atomicAdd(&curs[ld], 1);
        if (off < BKT_CAP) lsrc[off] = (int)(pk & 0xFFFFFFu);
    }
    __syncthreads();
    int lim = cnt < BKT_CAP ? cnt : BKT_CAP;
    for (int k = t; k < lim; k += 256) col[e0 + k] = lsrc[k];
}

// ---------------- fused GAT aggregation: 16-lane groups, 8 edges in flight ----------------
// layer1: h [n,128] bf16 (256B row = 16 lanes x 16B); out = relu(agg/den + b1) bf16
__global__ __launch_bounds__(256) void gat_agg1(const int* __restrict__ rowptr,
                                                const int* __restrict__ col,
                                                const ushort_t* __restrict__ h,
                                                const float* __restrict__ asrc,
                                                const float* __restrict__ adst,
                                                const float* __restrict__ b1,
                                                ushort_t* __restrict__ outb, int n) {
    int i = (blockIdx.x * blockDim.x + threadIdx.x) >> 6;
    if (i >= n) return;
    int lane = threadIdx.x & 63;
    int grp = lane >> 4, c = lane & 15;  // feats 8c..8c+7, head = c>>3
    int head = c >> 3;
    float ad = adst[2 * i + head];
    const u16x8* h8 = (const u16x8*)h;  // row = 16 u16x8
    float acc[8] = {};
    float den = 0.f;
    if (grp == 0) {  // self-loop
        float w = __expf(lrelu(asrc[2 * i + head] + ad));
        u16x8 hv = h8[(size_t)i * 16 + c];
#pragma unroll
        for (int j = 0; j < 8; ++j) acc[j] = bf2f(hv[j]) * w;
        den = w;
    }
    int e0 = rowptr[i], end = rowptr[i + 1];
    for (int e = e0; e < end; e += 8) {
        int iA = e + grp, iB = e + 4 + grp;
        bool vA = iA < end, vB = iB < end;
        int sA = col[vA ? iA : e0];
        int sB = col[vB ? iB : e0];
        float asA = asrc[2 * sA + head];
        float asB = asrc[2 * sB + head];
        u16x8 hA = h8[(size_t)sA * 16 + c];
        u16x8 hB = h8[(size_t)sB * 16 + c];
        float wA = vA ? __expf(lrelu(asA + ad)) : 0.f;
        float wB = vB ? __expf(lrelu(asB + ad)) : 0.f;
#pragma unroll
        for (int j = 0; j < 8; ++j) acc[j] = fmaf(bf2f(hA[j]), wA, acc[j]);
#pragma unroll
        for (int j = 0; j < 8; ++j) acc[j] = fmaf(bf2f(hB[j]), wB, acc[j]);
        den += wA + wB;
    }
#pragma unroll
    for (int j = 0; j < 8; ++j) {
        acc[j] += __shfl_xor(acc[j], 16);
        acc[j] += __shfl_xor(acc[j], 32);
    }
    den += __shfl_xor(den, 16);
    den += __shfl_xor(den, 32);
    if (grp == 0) {
        float inv = 1.f / den;
        u16x8 ov;
#pragma unroll
        for (int j = 0; j < 8; ++j) {
            float r = fmaf(acc[j], inv, b1[8 * c + j]);
            r = r > 0.f ? r : 0.f;
            ov[j] = f2bf(r);
        }
        *((u16x8*)outb + (size_t)i * 16 + c) = ov;
    }
}

// layer2: h [n,64] bf16 (128B row = 16 lanes x 8B); out fp32 [n,64]
__global__ __launch_bounds__(256) void gat_agg2(const int* __restrict__ rowptr,
                                                const int* __restrict__ col,
                                                const ushort_t* __restrict__ h,
                                                const float* __restrict__ asrc,
                                                const float* __restrict__ adst,
                                                float* __restrict__ outb, int n) {
    int i = (blockIdx.x * blockDim.x + threadIdx.x) >> 6;
    if (i >= n) return;
    int lane = threadIdx.x & 63;
    int grp = lane >> 4, c = lane & 15;  // feats 4c..4c+3
    float ad = adst[i];
    const u16x4* h4 = (const u16x4*)h;  // row = 16 u16x4
    float acc[4] = {};
    float den = 0.f;
    if (grp == 0) {
        float w = __expf(lrelu(asrc[i] + ad));
        u16x4 hv = h4[(size_t)i * 16 + c];
#pragma unroll
        for (int j = 0; j < 4; ++j) acc[j] = bf2f(hv[j]) * w;
        den = w;
    }
    int e0 = rowptr[i], end = rowptr[i + 1];
    for (int e = e0; e < end; e += 8) {
        int iA = e + grp, iB = e + 4 + grp;
        bool vA = iA < end, vB = iB < end;
        int sA = col[vA ? iA : e0];
        int sB = col[vB ? iB : e0];
        float asA = asrc[sA];
        float asB = asrc[sB];
        u16x4 hA = h4[(size_t)sA * 16 + c];
        u16x4 hB = h4[(size_t)sB * 16 + c];
        float wA = vA ? __expf(lrelu(asA + ad)) : 0.f;
        float wB = vB ? __expf(lrelu(asB + ad)) : 0.f;
#pragma unroll
        for (int j = 0; j < 4; ++j) acc[j] = fmaf(bf2f(hA[j]), wA, acc[j]);
#pragma unroll
        for (int j = 0; j < 4; ++j) acc[j] = fmaf(bf2f(hB[j]), wB, acc[j]);
        den += wA + wB;
    }
#pragma unroll
    for (int j = 0; j < 4; ++j) {
        acc[j] += __shfl_xor(acc[j], 16);
        acc[j] += __shfl_xor(acc[j], 32);
    }
    den += __shfl_xor(den, 16);
    den += __shfl_xor(den, 32);
    if (grp == 0) {
        float inv = 1.f / den;
        float4 o = {acc[0] * inv, acc[1] * inv, acc[2] * inv, acc[3] * inv};
        *((float4*)outb + (size_t)i * 16 + c) = o;
    }
}

// ---------------- mean pool (batch sorted) ----------------
#define NPB 256
__global__ __launch_bounds__(256) void pool_kernel(const float* __restrict__ h,
                                                   const int* __restrict__ batch,
                                                   float* __restrict__ sums,
                                                   float* __restrict__ cnt, int n) {
    __shared__ float ls[GRAPHS * HIDC];
    __shared__ float lc[GRAPHS];
    int base = blockIdx.x * NPB;
    for (int t = threadIdx.x; t < GRAPHS * HIDC; t += blockDim.x) ls[t] = 0.f;
    for (int t = threadIdx.x; t < GRAPHS; t += blockDim.x) lc[t] = 0.f;
    __syncthreads();
    int wave = threadIdx.x >> 6, lane = threadIdx.x & 63;
    int end = base + NPB < n ? base + NPB : n;
    for (int i = base + wave; i < end; i += 4) {
        int g = batch[i];
        unsafeAtomicAdd(&ls[g * HIDC + lane], h[(size_t)i * HIDC + lane]);
        if (lane == 0) unsafeAtomicAdd(&lc[g], 1.f);
    }
    __syncthreads();
    int gmin = batch[base];
    int gmax = batch[end - 1];
    int ng = gmax - gmin + 1;
    for (int t = threadIdx.x; t < ng * HIDC; t += blockDim.x) {
        int g = gmin + t / HIDC, c = t % HIDC;
        atomAddG(&sums[g * HIDC + c], ls[g * HIDC + c]);
    }
    for (int g = gmin + (int)threadIdx.x; g <= gmax; g += blockDim.x)
        atomAddG(&cnt[g], lc[g]);
}

// ---------------- final linear ----------------
__global__ void final_kernel(const float* __restrict__ sums, const float* __restrict__ cnt,
                             const float* __restrict__ b2, const float* __restrict__ Wl,
                             const float* __restrict__ bl, float* __restrict__ out) {
    int t = blockIdx.x * blockDim.x + threadIdx.x;
    if (t < GRAPHS * OUTC) {
        int g = t / OUTC, o = t % OUTC;
        float c = cnt[g];
        c = c > 1.f ? c : 1.f;
        float inv = 1.f / c;
        float acc = bl[o];
        for (int k = 0; k < HIDC; ++k)
            acc += (sums[g * HIDC + k] * inv + b2[k]) * Wl[k * OUTC + o];
        out[t] = acc;
    }
}

extern "C" void kernel_launch(void* const* d_in, const int* in_sizes, int n_in, void* d_out,
                              int out_size, void* d_ws, size_t ws_size, hipStream_t stream) {
    const float* x = (const float*)d_in[0];
    const int* ei = (const int*)d_in[1];
    const int* batch = (const int*)d_in[2];
    const float* W1 = (const float*)d_in[3];
    const float* att_src1 = (const float*)d_in[4];
    const float* att_dst1 = (const float*)d_in[5];
    const float* b1 = (const float*)d_in[6];
    const float* W2 = (const float*)d_in[7];
    const float* att_src2 = (const float*)d_in[8];
    const float* att_dst2 = (const float*)d_in[9];
    const float* b2 = (const float*)d_in[10];
    const float* Wl = (const float*)d_in[11];
    const float* bl = (const float*)d_in[12];
    float* out = (float*)d_out;

    const int n = in_sizes[2];
    const int E = in_sizes[1] / 2;

    char* p = (char*)d_ws;
    auto alloc = [&](size_t bytes) {
        char* r = p;
        p += (bytes + 255) & ~(size_t)255;
        return r;
    };
    ushort_t* h1 = (ushort_t*)alloc((size_t)n * 128 * 2);
    ushort_t* hrelu = (ushort_t*)alloc((size_t)n * 128 * 2);
    ushort_t* h2 = (ushort_t*)alloc((size_t)n * 64 * 2);
    float* conv2 = (float*)alloc((size_t)n * 64 * 4);
    float* asrc1 = (float*)alloc((size_t)n * 2 * 4);
    float* adst1 = (float*)alloc((size_t)n * 2 * 4);
    float* asrc2 = (float*)alloc((size_t)n * 4);
    float* adst2 = (float*)alloc((size_t)n * 4);
    float* sums = (float*)alloc(GRAPHS * HIDC * 4);
    float* cnt = (float*)alloc(GRAPHS * 4);
    int* bcnt = (int*)alloc(MAXNB * 4);
    int* bbase = (int*)alloc((MAXNB + 1) * 4);
    int* bcursor = (int*)alloc(MAXNB * 4);
    int* rowptr = (int*)alloc(((size_t)n + 1) * 4);
    unsigned int* ebuf = (unsigned int*)alloc((size_t)E * 4);
    int* col = (int*)alloc((size_t)E * 4);

    const int NB = (n + 255) >> BSHIFT;
    const int gblk = (n + 63) / 64;

    // ---- CSR build via two-level bucket sort ----
    hipMemsetAsync(bcnt, 0, NB * sizeof(int), stream);
    bucket_hist<<<512, 256, 0, stream>>>(ei, E, bcnt, NB);
    bucket_scan<<<1, 512, 0, stream>>>(bcnt, bbase, bcursor, rowptr, NB, n, E);
    bucket_scatter<<<512, 256, 0, stream>>>(ei, E, bcursor, ebuf, NB);
    bucket_build<<<NB, 256, 0, stream>>>(ebuf, bbase, rowptr, col, n);

    // ---- layer 1 ----
    mfma_gemm<false><<<dim3(gblk, 2), 256, 0, stream>>>(x, W1, h1, n, 128, 128);
    alpha1_kernel<<<2048, 256, 0, stream>>>(h1, att_src1, att_dst1, asrc1, adst1, n);
    gat_agg1<<<(n + 3) / 4, 256, 0, stream>>>(rowptr, col, h1, asrc1, adst1, b1, hrelu, n);

    // ---- layer 2 ----
    mfma_gemm<true><<<dim3(gblk, 1), 256, 0, stream>>>(hrelu, W2, h2, n, 128, 64);
    alpha2_kernel<<<2048, 256, 0, stream>>>(h2, att_src2, att_dst2, asrc2, adst2, n);
    gat_agg2<<<(n + 3) / 4, 256, 0, stream>>>(rowptr, col, h2, asrc2, adst2, conv2, n);

    // ---- pool + final (b2 folded into final) ----
    hipMemsetAsync(sums, 0, (GRAPHS * HIDC + GRAPHS) * sizeof(float), stream);
    pool_kernel<<<(n + NPB - 1) / NPB, 256, 0, stream>>>(conv2, batch, sums, cnt, n);
    final_kernel<<<(GRAPHS * OUTC + 255) / 256, 256, 0, stream>>>(sums, cnt, b2, Wl, bl, out);
}

// Round 8
// 363.241 us; speedup vs baseline: 4.3233x; 1.0914x over previous
//
#include <hip/hip_runtime.h>
#include <math.h>

#define GRAPHS 100
#define HIDC 64
#define OUTC 16
#define SLOPE 0.2f
#define BSHIFT 8
#define MAXNB 512
#define BKT_CAP 10240

typedef unsigned short ushort_t;
typedef short bf16x8 __attribute__((ext_vector_type(8)));
typedef float f32x4 __attribute__((ext_vector_type(4)));
typedef ushort_t u16x8 __attribute__((ext_vector_type(8)));
typedef ushort_t u16x4 __attribute__((ext_vector_type(4)));

__device__ __forceinline__ float lrelu(float v) { return v > 0.f ? v : SLOPE * v; }
__device__ __forceinline__ void atomAddG(float* p, float v) { unsafeAtomicAdd(p, v); }
__device__ __forceinline__ float bf2f(ushort_t u) {
    unsigned int x = ((unsigned int)u) << 16;
    return __builtin_bit_cast(float, x);
}
__device__ __forceinline__ ushort_t f2bf(float f) {
    unsigned int u = __builtin_bit_cast(unsigned int, f);
    u += 0x7FFFu + ((u >> 16) & 1u);  // RNE
    return (ushort_t)(u >> 16);
}
__device__ __forceinline__ unsigned int pack2(float lo, float hi) {
    return (unsigned int)f2bf(lo) | ((unsigned int)f2bf(hi) << 16);
}

// ------- MFMA bf16 GEMM + fused alpha epilogue -------
// C_bf16[M,N] = A[M,K] @ W_f32[K,N]; also asrc/adst[ASTRIDE*row + blockIdx.y] =
// sum_c h[row,c]*att_src[col0+c] (head == blockIdx.y; valid because head split == 64-col block).
template <bool A_IS_BF16, int ASTRIDE>
__global__ __launch_bounds__(256) void mfma_gemm_alpha(const void* __restrict__ Av,
                                                       const float* __restrict__ W,
                                                       ushort_t* __restrict__ Cbf,
                                                       const float* __restrict__ att_src,
                                                       const float* __restrict__ att_dst,
                                                       float* __restrict__ asrc,
                                                       float* __restrict__ adst,
                                                       int M, int K, int N) {
    __shared__ ushort_t As[64 * 40];
    __shared__ ushort_t Bs[64 * 40];
    __shared__ float ps[2][64], pd[2][64];
    const int tid = threadIdx.x;
    const int row0 = blockIdx.x * 64;
    const int col0 = blockIdx.y * 64;
    const int lane = tid & 63;
    const int wv = tid >> 6;
    const int wr = (wv >> 1) * 32, wc = (wv & 1) * 32;
    const int l15 = lane & 15, l4 = lane >> 4;

    const int srow = tid >> 2;
    const int skoff = (tid & 3) * 8;
    const int bc = tid & 63, bk = (tid >> 6) * 8;

    f32x4 acc[2][2] = {};

    for (int k0 = 0; k0 < K; k0 += 32) {
        {
            int gr = row0 + srow;
            uint4 v = {0u, 0u, 0u, 0u};
            if (gr < M) {
                if (A_IS_BF16) {
                    const ushort_t* Ab = (const ushort_t*)Av;
                    v = *(const uint4*)(Ab + (size_t)gr * K + k0 + skoff);
                } else {
                    const float* Af = (const float*)Av;
                    const float4 a0 = *(const float4*)(Af + (size_t)gr * K + k0 + skoff);
                    const float4 a1 = *(const float4*)(Af + (size_t)gr * K + k0 + skoff + 4);
                    v.x = pack2(a0.x, a0.y);
                    v.y = pack2(a0.z, a0.w);
                    v.z = pack2(a1.x, a1.y);
                    v.w = pack2(a1.z, a1.w);
                }
            }
            *(uint4*)&As[srow * 40 + skoff] = v;
        }
        {
#pragma unroll
            for (int j = 0; j < 8; ++j) {
                float w = W[(size_t)(k0 + bk + j) * N + col0 + bc];
                Bs[bc * 40 + bk + j] = f2bf(w);
            }
        }
        __syncthreads();
        bf16x8 af[2], bfr[2];
#pragma unroll
        for (int mi = 0; mi < 2; ++mi)
            af[mi] = *(const bf16x8*)&As[(wr + mi * 16 + l15) * 40 + l4 * 8];
#pragma unroll
        for (int ni = 0; ni < 2; ++ni)
            bfr[ni] = *(const bf16x8*)&Bs[(wc + ni * 16 + l15) * 40 + l4 * 8];
#pragma unroll
        for (int mi = 0; mi < 2; ++mi)
#pragma unroll
            for (int ni = 0; ni < 2; ++ni)
                acc[mi][ni] = __builtin_amdgcn_mfma_f32_16x16x32_bf16(af[mi], bfr[ni],
                                                                     acc[mi][ni], 0, 0, 0);
        __syncthreads();
    }
    // C write: D row = (lane>>4)*4 + r, col = lane&15
#pragma unroll
    for (int mi = 0; mi < 2; ++mi)
#pragma unroll
        for (int ni = 0; ni < 2; ++ni)
#pragma unroll
            for (int r = 0; r < 4; ++r) {
                int row = row0 + wr + mi * 16 + l4 * 4 + r;
                int colg = col0 + wc + ni * 16 + l15;
                if (row < M) Cbf[(size_t)row * N + colg] = f2bf(acc[mi][ni][r]);
            }
    // alpha epilogue
    float as_c[2], ad_c[2];
#pragma unroll
    for (int ni = 0; ni < 2; ++ni) {
        int cidx = col0 + wc + ni * 16 + l15;
        as_c[ni] = att_src[cidx];
        ad_c[ni] = att_dst[cidx];
    }
#pragma unroll
    for (int mi = 0; mi < 2; ++mi)
#pragma unroll
        for (int r = 0; r < 4; ++r) {
            float s = acc[mi][0][r] * as_c[0] + acc[mi][1][r] * as_c[1];
            float d = acc[mi][0][r] * ad_c[0] + acc[mi][1][r] * ad_c[1];
#pragma unroll
            for (int off = 1; off < 16; off <<= 1) {
                s += __shfl_xor(s, off);
                d += __shfl_xor(d, off);
            }
            if (l15 == 0) {
                int rl = wr + mi * 16 + l4 * 4 + r;
                ps[wc >> 5][rl] = s;
                pd[wc >> 5][rl] = d;
            }
        }
    __syncthreads();
    if (tid < 64) {
        int row = row0 + tid;
        if (row < M) {
            asrc[ASTRIDE * row + blockIdx.y] = ps[0][tid] + ps[1][tid];
            adst[ASTRIDE * row + blockIdx.y] = pd[0][tid] + pd[1][tid];
        }
    }
}

// ---------------- bucket-sort CSR build (dst -> list of src) ----------------
__global__ __launch_bounds__(256) void bucket_hist(const int* __restrict__ ei, int E,
                                                   int* __restrict__ bcnt, int NB) {
    __shared__ int h[MAXNB];
    for (int t = threadIdx.x; t < NB; t += 256) h[t] = 0;
    __syncthreads();
    int chunk = (E + gridDim.x - 1) / gridDim.x;
    int e0 = blockIdx.x * chunk;
    int e1 = e0 + chunk < E ? e0 + chunk : E;
    for (int e = e0 + threadIdx.x; e < e1; e += 256)
        atomicAdd(&h[ei[E + e] >> BSHIFT], 1);
    __syncthreads();
    for (int t = threadIdx.x; t < NB; t += 256)
        if (h[t]) atomicAdd(&bcnt[t], h[t]);
}

__global__ __launch_bounds__(512) void bucket_scan(const int* __restrict__ bcnt,
                                                   int* __restrict__ bbase,
                                                   int* __restrict__ bcursor,
                                                   int* __restrict__ rowptr,
                                                   int NB, int n, int E) {
    __shared__ int sh[512];
    int t = threadIdx.x;
    int v = (t < NB) ? bcnt[t] : 0;
    sh[t] = v;
    __syncthreads();
#pragma unroll
    for (int off = 1; off < 512; off <<= 1) {
        int val = (t >= off) ? sh[t - off] : 0;
        __syncthreads();
        sh[t] += val;
        __syncthreads();
    }
    if (t < NB) {
        int base = sh[t] - v;
        bbase[t] = base;
        bcursor[t] = base;
    }
    if (t == 0) {
        bbase[NB] = E;
        rowptr[n] = E;
    }
}

__global__ __launch_bounds__(256) void bucket_scatter(const int* __restrict__ ei, int E,
                                                      int* __restrict__ bcursor,
                                                      unsigned int* __restrict__ ebuf, int NB) {
    __shared__ int h[MAXNB];
    __shared__ int lbase[MAXNB];
    for (int t = threadIdx.x; t < NB; t += 256) h[t] = 0;
    __syncthreads();
    int chunk = (E + gridDim.x - 1) / gridDim.x;
    int e0 = blockIdx.x * chunk;
    int e1 = e0 + chunk < E ? e0 + chunk : E;
    for (int e = e0 + threadIdx.x; e < e1; e += 256)
        atomicAdd(&h[ei[E + e] >> BSHIFT], 1);
    __syncthreads();
    for (int t = threadIdx.x; t < NB; t += 256) {
        int c = h[t];
        lbase[t] = c ? atomicAdd(&bcursor[t], c) : 0;
        h[t] = 0;  // reuse as running cursor
    }
    __syncthreads();
    for (int e = e0 + threadIdx.x; e < e1; e += 256) {
        int d = ei[E + e];
        int s = ei[e];
        int b = d >> BSHIFT;
        int off = atomicAdd(&h[b], 1);
        ebuf[lbase[b] + off] = (unsigned)s | ((unsigned)(d & ((1 << BSHIFT) - 1)) << 24);
    }
}

__global__ __launch_bounds__(256) void bucket_build(const unsigned int* __restrict__ ebuf,
                                                    const int* __restrict__ bbase,
                                                    int* __restrict__ rowptr,
                                                    int* __restrict__ col, int n) {
    __shared__ int hist[256];
    __shared__ int curs[256];
    __shared__ int sh[256];
    __shared__ int lsrc[BKT_CAP];
    int b = blockIdx.x;
    int e0 = bbase[b], e1 = bbase[b + 1];
    int cnt = e1 - e0;
    int t = threadIdx.x;
    hist[t] = 0;
    __syncthreads();
    for (int k = t; k < cnt; k += 256) atomicAdd(&hist[ebuf[e0 + k] >> 24], 1);
    __syncthreads();
    int v = hist[t];
    sh[t] = v;
    __syncthreads();
#pragma unroll
    for (int off = 1; off < 256; off <<= 1) {
        int val = (t >= off) ? sh[t - off] : 0;
        __syncthreads();
        sh[t] += val;
        __syncthreads();
    }
    int ex = sh[t] - v;
    curs[t] = ex;
    int node = (b << BSHIFT) + t;
    if (node < n) rowptr[node] = e0 + ex;
    __syncthreads();
    for (int k = t; k < cnt; k += 256) {
        unsigned pk = ebuf[e0 + k];
        int ld = pk >> 24;
        int off = atomicAdd(&curs[ld], 1);
        if (off < BKT_CAP) lsrc[off] = (int)(pk & 0xFFFFFFu);
    }
    __syncthreads();
    int lim = cnt < BKT_CAP ? cnt : BKT_CAP;
    for (int k = t; k < lim; k += 256) col[e0 + k] = lsrc[k];
}

// ---------------- fused GAT aggregation: 16-lane groups, 16 edges in flight ----------------
// layer1: h [n,128] bf16; out = relu(agg/den + b1) bf16
__global__ __launch_bounds__(256) void gat_agg1(const int* __restrict__ rowptr,
                                                const int* __restrict__ col,
                                                const ushort_t* __restrict__ h,
                                                const float* __restrict__ asrc,
                                                const float* __restrict__ adst,
                                                const float* __restrict__ b1,
                                                ushort_t* __restrict__ outb, int n) {
    int i = (blockIdx.x * blockDim.x + threadIdx.x) >> 6;
    if (i >= n) return;
    int lane = threadIdx.x & 63;
    int grp = lane >> 4, c = lane & 15;  // feats 8c..8c+7, head = c>>3
    int head = c >> 3;
    float ad = adst[2 * i + head];
    const u16x8* h8 = (const u16x8*)h;
    float acc[8] = {};
    float den = 0.f;
    if (grp == 0) {  // self-loop
        float w = __expf(lrelu(asrc[2 * i + head] + ad));
        u16x8 hv = h8[(size_t)i * 16 + c];
#pragma unroll
        for (int j = 0; j < 8; ++j) acc[j] = bf2f(hv[j]) * w;
        den = w;
    }
    int e0 = rowptr[i], end = rowptr[i + 1];
    for (int e = e0; e < end; e += 16) {
        float wv[4];
        u16x8 hv[4];
#pragma unroll
        for (int q = 0; q < 4; ++q) {
            int idx = e + 4 * q + grp;
            bool vld = idx < end;
            int s = col[vld ? idx : e0];
            float as = asrc[2 * s + head];
            hv[q] = h8[(size_t)s * 16 + c];
            wv[q] = vld ? __expf(lrelu(as + ad)) : 0.f;
        }
#pragma unroll
        for (int q = 0; q < 4; ++q) {
#pragma unroll
            for (int j = 0; j < 8; ++j) acc[j] = fmaf(bf2f(hv[q][j]), wv[q], acc[j]);
            den += wv[q];
        }
    }
#pragma unroll
    for (int j = 0; j < 8; ++j) {
        acc[j] += __shfl_xor(acc[j], 16);
        acc[j] += __shfl_xor(acc[j], 32);
    }
    den += __shfl_xor(den, 16);
    den += __shfl_xor(den, 32);
    if (grp == 0) {
        float inv = 1.f / den;
        u16x8 ov;
#pragma unroll
        for (int j = 0; j < 8; ++j) {
            float r = fmaf(acc[j], inv, b1[8 * c + j]);
            r = r > 0.f ? r : 0.f;
            ov[j] = f2bf(r);
        }
        *((u16x8*)outb + (size_t)i * 16 + c) = ov;
    }
}

// layer2: h [n,64] bf16, 1 head; out bf16 [n,64]
__global__ __launch_bounds__(256) void gat_agg2(const int* __restrict__ rowptr,
                                                const int* __restrict__ col,
                                                const ushort_t* __restrict__ h,
                                                const float* __restrict__ asrc,
                                                const float* __restrict__ adst,
                                                ushort_t* __restrict__ outb, int n) {
    int i = (blockIdx.x * blockDim.x + threadIdx.x) >> 6;
    if (i >= n) return;
    int lane = threadIdx.x & 63;
    int grp = lane >> 4, c = lane & 15;  // feats 4c..4c+3
    float ad = adst[i];
    const u16x4* h4 = (const u16x4*)h;
    float acc[4] = {};
    float den = 0.f;
    if (grp == 0) {
        float w = __expf(lrelu(asrc[i] + ad));
        u16x4 hv = h4[(size_t)i * 16 + c];
#pragma unroll
        for (int j = 0; j < 4; ++j) acc[j] = bf2f(hv[j]) * w;
        den = w;
    }
    int e0 = rowptr[i], end = rowptr[i + 1];
    for (int e = e0; e < end; e += 16) {
        float wv[4];
        u16x4 hv[4];
#pragma unroll
        for (int q = 0; q < 4; ++q) {
            int idx = e + 4 * q + grp;
            bool vld = idx < end;
            int s = col[vld ? idx : e0];
            float as = asrc[s];
            hv[q] = h4[(size_t)s * 16 + c];
            wv[q] = vld ? __expf(lrelu(as + ad)) : 0.f;
        }
#pragma unroll
        for (int q = 0; q < 4; ++q) {
#pragma unroll
            for (int j = 0; j < 4; ++j) acc[j] = fmaf(bf2f(hv[q][j]), wv[q], acc[j]);
            den += wv[q];
        }
    }
#pragma unroll
    for (int j = 0; j < 4; ++j) {
        acc[j] += __shfl_xor(acc[j], 16);
        acc[j] += __shfl_xor(acc[j], 32);
    }
    den += __shfl_xor(den, 16);
    den += __shfl_xor(den, 32);
    if (grp == 0) {
        float inv = 1.f / den;
        u16x4 ov = {f2bf(acc[0] * inv), f2bf(acc[1] * inv), f2bf(acc[2] * inv),
                    f2bf(acc[3] * inv)};
        *((u16x4*)outb + (size_t)i * 16 + c) = ov;
    }
}

// ---------------- mean pool (batch sorted), bf16 input ----------------
#define NPB 256
__global__ __launch_bounds__(256) void pool_kernel(const ushort_t* __restrict__ h,
                                                   const int* __restrict__ batch,
                                                   float* __restrict__ sums,
                                                   float* __restrict__ cnt, int n) {
    __shared__ float ls[GRAPHS * HIDC];
    __shared__ float lc[GRAPHS];
    int base = blockIdx.x * NPB;
    for (int t = threadIdx.x; t < GRAPHS * HIDC; t += blockDim.x) ls[t] = 0.f;
    for (int t = threadIdx.x; t < GRAPHS; t += blockDim.x) lc[t] = 0.f;
    __syncthreads();
    int wave = threadIdx.x >> 6, lane = threadIdx.x & 63;
    int end = base + NPB < n ? base + NPB : n;
    for (int i = base + wave; i < end; i += 4) {
        int g = batch[i];
        unsafeAtomicAdd(&ls[g * HIDC + lane], bf2f(h[(size_t)i * HIDC + lane]));
        if (lane == 0) unsafeAtomicAdd(&lc[g], 1.f);
    }
    __syncthreads();
    int gmin = batch[base];
    int gmax = batch[end - 1];
    int ng = gmax - gmin + 1;
    for (int t = threadIdx.x; t < ng * HIDC; t += blockDim.x) {
        int g = gmin + t / HIDC, c = t % HIDC;
        atomAddG(&sums[g * HIDC + c], ls[g * HIDC + c]);
    }
    for (int g = gmin + (int)threadIdx.x; g <= gmax; g += blockDim.x)
        atomAddG(&cnt[g], lc[g]);
}

// ---------------- final linear ----------------
__global__ void final_kernel(const float* __restrict__ sums, const float* __restrict__ cnt,
                             const float* __restrict__ b2, const float* __restrict__ Wl,
                             const float* __restrict__ bl, float* __restrict__ out) {
    int t = blockIdx.x * blockDim.x + threadIdx.x;
    if (t < GRAPHS * OUTC) {
        int g = t / OUTC, o = t % OUTC;
        float c = cnt[g];
        c = c > 1.f ? c : 1.f;
        float inv = 1.f / c;
        float acc = bl[o];
        for (int k = 0; k < HIDC; ++k)
            acc += (sums[g * HIDC + k] * inv + b2[k]) * Wl[k * OUTC + o];
        out[t] = acc;
    }
}

extern "C" void kernel_launch(void* const* d_in, const int* in_sizes, int n_in, void* d_out,
                              int out_size, void* d_ws, size_t ws_size, hipStream_t stream) {
    const float* x = (const float*)d_in[0];
    const int* ei = (const int*)d_in[1];
    const int* batch = (const int*)d_in[2];
    const float* W1 = (const float*)d_in[3];
    const float* att_src1 = (const float*)d_in[4];
    const float* att_dst1 = (const float*)d_in[5];
    const float* b1 = (const float*)d_in[6];
    const float* W2 = (const float*)d_in[7];
    const float* att_src2 = (const float*)d_in[8];
    const float* att_dst2 = (const float*)d_in[9];
    const float* b2 = (const float*)d_in[10];
    const float* Wl = (const float*)d_in[11];
    const float* bl = (const float*)d_in[12];
    float* out = (float*)d_out;

    const int n = in_sizes[2];
    const int E = in_sizes[1] / 2;

    char* p = (char*)d_ws;
    auto alloc = [&](size_t bytes) {
        char* r = p;
        p += (bytes + 255) & ~(size_t)255;
        return r;
    };
    ushort_t* h1 = (ushort_t*)alloc((size_t)n * 128 * 2);
    ushort_t* hrelu = (ushort_t*)alloc((size_t)n * 128 * 2);
    ushort_t* h2 = (ushort_t*)alloc((size_t)n * 64 * 2);
    ushort_t* conv2 = (ushort_t*)alloc((size_t)n * 64 * 2);
    float* asrc1 = (float*)alloc((size_t)n * 2 * 4);
    float* adst1 = (float*)alloc((size_t)n * 2 * 4);
    float* asrc2 = (float*)alloc((size_t)n * 4);
    float* adst2 = (float*)alloc((size_t)n * 4);
    float* sums = (float*)alloc(GRAPHS * HIDC * 4);
    float* cnt = (float*)alloc(GRAPHS * 4);
    int* bcnt = (int*)alloc(MAXNB * 4);
    int* bbase = (int*)alloc((MAXNB + 1) * 4);
    int* bcursor = (int*)alloc(MAXNB * 4);
    int* rowptr = (int*)alloc(((size_t)n + 1) * 4);
    unsigned int* ebuf = (unsigned int*)alloc((size_t)E * 4);
    int* col = (int*)alloc((size_t)E * 4);

    const int NB = (n + 255) >> BSHIFT;
    const int gblk = (n + 63) / 64;

    // ---- CSR build via two-level bucket sort ----
    hipMemsetAsync(bcnt, 0, NB * sizeof(int), stream);
    bucket_hist<<<512, 256, 0, stream>>>(ei, E, bcnt, NB);
    bucket_scan<<<1, 512, 0, stream>>>(bcnt, bbase, bcursor, rowptr, NB, n, E);
    bucket_scatter<<<512, 256, 0, stream>>>(ei, E, bcursor, ebuf, NB);
    bucket_build<<<NB, 256, 0, stream>>>(ebuf, bbase, rowptr, col, n);

    // ---- layer 1 (alpha fused into GEMM epilogue) ----
    mfma_gemm_alpha<false, 2><<<dim3(gblk, 2), 256, 0, stream>>>(
        x, W1, h1, att_src1, att_dst1, asrc1, adst1, n, 128, 128);
    gat_agg1<<<(n + 3) / 4, 256, 0, stream>>>(rowptr, col, h1, asrc1, adst1, b1, hrelu, n);

    // ---- layer 2 ----
    mfma_gemm_alpha<true, 1><<<dim3(gblk, 1), 256, 0, stream>>>(
        hrelu, W2, h2, att_src2, att_dst2, asrc2, adst2, n, 128, 64);
    gat_agg2<<<(n + 3) / 4, 256, 0, stream>>>(rowptr, col, h2, asrc2, adst2, conv2, n);

    // ---- pool + final (b2 folded into final) ----
    hipMemsetAsync(sums, 0, (GRAPHS * HIDC + GRAPHS) * sizeof(float), stream);
    pool_kernel<<<(n + NPB - 1) / NPB, 256, 0, stream>>>(conv2, batch, sums, cnt, n);
    final_kernel<<<(GRAPHS * OUTC + 255) / 256, 256, 0, stream>>>(sums, cnt, b2, Wl, bl, out);
}